// Round 10
// baseline (117.335 us; speedup 1.0000x reference)
//
#include <hip/hip_runtime.h>

#define BB 32
#define TT 64
#define NN 128
#define FF 128
#define UU 64
#define K1 64
#define K2 32
#define G4 256
#define EPSV 1e-3f
#define SLOPE 0.01f

#define ALD 136   // a row stride in bf16 elems (128 + 8 pad)
#define SLD 136   // sup2T row stride
#define WLD 72    // w2T row stride

typedef __attribute__((ext_vector_type(8))) short short8;
typedef __attribute__((ext_vector_type(4))) float f32x4;
typedef __attribute__((ext_vector_type(2))) __fp16 half2v;

__device__ __forceinline__ float sigmoidf_(float x) {
  return __builtin_amdgcn_rcpf(1.f + __expf(-x));
}
__device__ __forceinline__ float tanhf_(float x) {
  return 1.f - 2.f * __builtin_amdgcn_rcpf(__expf(2.f * x) + 1.f);
}
__device__ __forceinline__ float leaky_(float x) { return x >= 0.f ? x : SLOPE * x; }
__device__ __forceinline__ unsigned short f2bf(float x) {
  union { float f; unsigned u; } v; v.f = x;
  unsigned r = v.u + 0x7fff + ((v.u >> 16) & 1);
  return (unsigned short)(r >> 16);
}

// ---- prep (0..31) + xz GEMM (32..287) + d1w reorder via LDS transpose (288..351) ----
__global__ __launch_bounds__(256) void k_pre(const float* __restrict__ x,
                                             const float* __restrict__ wk,
                                             const float* __restrict__ bias,
                                             const float* __restrict__ a,
                                             const float* __restrict__ w2,
                                             const float* __restrict__ wr,
                                             const float* __restrict__ w1,
                                             const float* __restrict__ d1w,
                                             float* __restrict__ xz,
                                             float* __restrict__ rsum,
                                             unsigned short* __restrict__ apad,
                                             unsigned short* __restrict__ w2t,
                                             unsigned* __restrict__ wrp,
                                             unsigned* __restrict__ w1p,
                                             float4* __restrict__ d1r) {
  int tid = threadIdx.x;
  if (blockIdx.x < 32) {
    int b = blockIdx.x;
    int wave = tid >> 6, lane = tid & 63;
    const float* ab = a + (size_t)b * NN * NN;
    for (int r = 0; r < 32; ++r) {
      int row = wave * 32 + r;
      float2 v = *(const float2*)(ab + (size_t)row * NN + lane * 2);
      float s = v.x + v.y;
#pragma unroll
      for (int off = 32; off >= 1; off >>= 1) s += __shfl_down(s, off);
      if (lane == 0) rsum[b * NN + row] = s;
    }
    unsigned short* ap = apad + (size_t)b * NN * ALD;
    for (int idx = tid; idx < NN * NN; idx += 256) {
      int i = idx >> 7, j = idx & 127;
      ap[i * ALD + j] = f2bf(ab[idx]);
    }
    if (b == 0) {
      for (int idx = tid; idx < K1 * K2; idx += 256) {
        int k = idx >> 5, m = idx & 31;
        w2t[m * WLD + k] = f2bf(w2[idx]);
      }
    }
    if (b == 1) {
      // pack Wr f16x2, LANE-CONTIGUOUS: wrp[u*128 + gate*32 + p]
      for (int idx = tid; idx < 4 * 32 * UU; idx += 256) {
        int p = idx & 31;
        int gate = (idx >> 5) & 3;
        int u = idx >> 7;
        int col = gate * UU + u;
        union { __fp16 h[2]; unsigned u; } pk;
        pk.h[0] = (__fp16)wr[(2 * p) * G4 + col];
        pk.h[1] = (__fp16)wr[(2 * p + 1) * G4 + col];
        wrp[idx] = pk.u;
      }
    }
    if (b == 2) {
      // pack w1 f16x2, LANE-CONTIGUOUS: w1p[k*32 + p]
      for (int idx = tid; idx < 32 * K1; idx += 256) {
        int p = idx & 31, k = idx >> 5;
        union { __fp16 h[2]; unsigned u; } pk;
        pk.h[0] = (__fp16)w1[(2 * p) * K1 + k];
        pk.h[1] = (__fp16)w1[(2 * p + 1) * K1 + k];
        w1p[idx] = pk.u;
      }
    }
  } else if (blockIdx.x < 288) {
    __shared__ float xs[8][FF];
    int row0 = (blockIdx.x - 32) * 8;
    for (int i = tid; i < 8 * FF; i += 256) xs[i >> 7][i & 127] = x[(size_t)row0 * FF + i];
    __syncthreads();
    int g = tid;
    float acc[8];
    float bg = bias[g];
#pragma unroll
    for (int r = 0; r < 8; ++r) acc[r] = bg;
    for (int f = 0; f < FF; ++f) {
      float w = wk[f * G4 + g];
#pragma unroll
      for (int r = 0; r < 8; ++r) acc[r] += xs[r][f] * w;
    }
#pragma unroll
    for (int r = 0; r < 8; ++r) xz[(size_t)(row0 + r) * G4 + g] = acc[r];
  } else {
    // d1w -> d1r (MFMA C-fragment order) via LDS transpose; block = t, 4 chunks of 32 rows
    int t = blockIdx.x - 288;
    __shared__ float dt[3072];  // 12 KB: 32 rows x 32 m x 3 c
    const float* src = d1w + (size_t)t * NN * K2 * 3;
    for (int c32 = 0; c32 < 4; ++c32) {
      __syncthreads();  // protect previous chunk's reads
      for (int i = tid; i < 768; i += 256)
        ((float4*)dt)[i] = ((const float4*)(src + c32 * 3072))[i];
      __syncthreads();
#pragma unroll
      for (int q = 0; q < 3; ++q) {
        int item = q * 256 + tid;
        int l = item & 63;
        int gc = item >> 6;          // 0..11
        int g = gc / 3, c = gc % 3;
        int it = g >> 1, mt = g & 1;
        int l15v = l & 15, l4v = l >> 4;
        int m = mt * 16 + l15v;
        int rowbase = it * 16 + l4v * 4;
        float4 v;
        v.x = dt[(rowbase + 0) * 96 + m * 3 + c];
        v.y = dt[(rowbase + 1) * 96 + m * 3 + c];
        v.z = dt[(rowbase + 2) * 96 + m * 3 + c];
        v.w = dt[(rowbase + 3) * 96 + m * 3 + c];
        d1r[(((size_t)t * 4 + g) * 3 + c) * 256 + c32 * 64 + l] = v;
      }
    }
  }
}

// ---------------- LSTM scan: 8 independent wave-scans per block, 2 waves/SIMD ----------------
// wave = batch; lane u owns unit u (all 4 gates, 128 fdot2/step). No barriers at all:
// h broadcast via wave-private 128B LDS (in-order LDS pipe); xz from global with
// 1-step register prefetch (no barrier -> latency hidden by the co-resident wave).
// 2 waves/SIMD interleave -> exposed latencies of one wave fill the other's stalls.
__global__ __launch_bounds__(512, 2) void k_lstm(const float* __restrict__ xz,
                                                 const unsigned* __restrict__ wrp,
                                                 const unsigned* __restrict__ w1p,
                                                 const float* __restrict__ bnl_g,
                                                 const float* __restrict__ bnl_b,
                                                 const float* __restrict__ bnl_m,
                                                 const float* __restrict__ bnl_v,
                                                 float* __restrict__ s1out) {
  __shared__ __align__(16) __fp16 hp[8][TT * UU];  // 64 KB: bn'd h history per wave
  __shared__ __align__(16) __fp16 h16[8][UU];      // 1 KB: raw-h broadcast per wave
  int tid = threadIdx.x;
  int wave = tid >> 6, lane = tid & 63;
  int b = blockIdx.x * 8 + wave;

  // weights: lane-contiguous 128 dwords -> 32 dwordx4 loads
  unsigned wv[4][32];
  {
    const uint4* wp = (const uint4*)(wrp + (size_t)lane * 128);
#pragma unroll
    for (int k = 0; k < 32; ++k) {
      uint4 v = wp[k];
      int gate = k >> 3, p0 = (k & 7) * 4;
      wv[gate][p0 + 0] = v.x; wv[gate][p0 + 1] = v.y;
      wv[gate][p0 + 2] = v.z; wv[gate][p0 + 3] = v.w;
    }
  }
  float bscale = bnl_g[lane] * rsqrtf(bnl_v[lane] + EPSV);
  float boff = bnl_b[lane] - bnl_m[lane] * bscale;
  h16[wave][lane] = (__fp16)0.f;
  float c = 0.f;

  const float* xzb = xz + (size_t)b * TT * G4;
  __fp16* hpw = &hp[wave][0];
  float czi = xzb[lane], czf = xzb[64 + lane], czg = xzb[128 + lane], czo = xzb[192 + lane];

  for (int t = 0; t < TT; ++t) {
    // prefetch next step's xz (used next iteration -> full step of slack)
    int tn = (t + 1 < TT) ? t + 1 : t;
    const float* nb = xzb + tn * G4;
    float nzi = nb[lane], nzf = nb[64 + lane], nzg = nb[128 + lane], nzo = nb[192 + lane];
    // broadcast-read h (uniform addresses), statically unpacked
    unsigned hw[32];
    {
      const uint4* hq = (const uint4*)&h16[wave][0];
#pragma unroll
      for (int k = 0; k < 8; ++k) {
        uint4 v = hq[k];
        hw[4 * k + 0] = v.x; hw[4 * k + 1] = v.y; hw[4 * k + 2] = v.z; hw[4 * k + 3] = v.w;
      }
    }
    float zi = czi, zf = czf, zg = czg, zo = czo;
#pragma unroll
    for (int p = 0; p < 32; ++p) {
      half2v hh = __builtin_bit_cast(half2v, hw[p]);
      zi = __builtin_amdgcn_fdot2(__builtin_bit_cast(half2v, wv[0][p]), hh, zi, false);
      zf = __builtin_amdgcn_fdot2(__builtin_bit_cast(half2v, wv[1][p]), hh, zf, false);
      zg = __builtin_amdgcn_fdot2(__builtin_bit_cast(half2v, wv[2][p]), hh, zg, false);
      zo = __builtin_amdgcn_fdot2(__builtin_bit_cast(half2v, wv[3][p]), hh, zo, false);
    }
    float i_ = sigmoidf_(zi), f_ = sigmoidf_(zf), g_ = tanhf_(zg), o_ = sigmoidf_(zo);
    c = f_ * c + i_ * g_;
    float h = o_ * tanhf_(c);
    h16[wave][lane] = (__fp16)h;                 // in-order LDS pipe within the wave
    hpw[t * UU + lane] = (__fp16)(h * bscale + boff);
    czi = nzi; czf = nzf; czg = nzg; czo = nzo;
  }

  // s1 tail: s1[t,k] = hp[t] . w1[:,k]  (lane = k), per-wave, no barrier needed
  unsigned w1v[32];
  {
    const uint4* wp1 = (const uint4*)(w1p + (size_t)lane * 32);
#pragma unroll
    for (int k = 0; k < 8; ++k) {
      uint4 v = wp1[k];
      w1v[4 * k + 0] = v.x; w1v[4 * k + 1] = v.y; w1v[4 * k + 2] = v.z; w1v[4 * k + 3] = v.w;
    }
  }
  float* s1b = s1out + (size_t)b * TT * K1;
  for (int t = 0; t < TT; ++t) {
    unsigned hw2[32];
    {
      const uint4* hq = (const uint4*)(hpw + t * UU);
#pragma unroll
      for (int k = 0; k < 8; ++k) {
        uint4 v = hq[k];
        hw2[4 * k + 0] = v.x; hw2[4 * k + 1] = v.y; hw2[4 * k + 2] = v.z; hw2[4 * k + 3] = v.w;
      }
    }
    float acc = 0.f;
#pragma unroll
    for (int p = 0; p < 32; ++p)
      acc = __builtin_amdgcn_fdot2(__builtin_bit_cast(half2v, w1v[p]),
                                   __builtin_bit_cast(half2v, hw2[p]), acc, false);
    s1b[t * K1 + lane] = acc;
  }
}

// ---------------- fused GCN1+GCN2+d1 partial, one block per (t,b), t-major ----------------
__global__ __launch_bounds__(256) void k_gcn(
    const float* __restrict__ s1g, const float* __restrict__ rsum,
    const unsigned short* __restrict__ apad, const unsigned short* __restrict__ w2t,
    const float* __restrict__ b1,
    const float* __restrict__ bn1_g, const float* __restrict__ bn1_b,
    const float* __restrict__ bn1_m, const float* __restrict__ bn1_v,
    const float* __restrict__ b2,
    const float* __restrict__ bn2_g, const float* __restrict__ bn2_b,
    const float* __restrict__ bn2_m, const float* __restrict__ bn2_v,
    const float4* __restrict__ d1r, float* __restrict__ part) {
  __shared__ unsigned short a_lds[NN * ALD];
  __shared__ unsigned short s2_lds[K2 * SLD];
  __shared__ unsigned short w2_lds[K2 * WLD];
  __shared__ float4 gp[K1];
  __shared__ float r_lds[NN];
  __shared__ float p2[3 * K2];
  __shared__ float red[12];

  int blk = blockIdx.x;
  int b = blk & 31, t = blk >> 5;   // t-major
  int tid = threadIdx.x;
  int lane = tid & 63, wave = tid >> 6;
  int l15 = lane & 15, l4 = lane >> 4;

  {
    const uint4* src = (const uint4*)(apad + (size_t)b * NN * ALD);
    uint4* dst = (uint4*)a_lds;
    for (int i = tid; i < NN * ALD / 8; i += 256) dst[i] = src[i];
  }
  {
    const uint2* src = (const uint2*)w2t;
    uint2* dst = (uint2*)w2_lds;
    for (int i = tid; i < K2 * WLD / 4; i += 256) dst[i] = src[i];
  }
  if (tid < K1) {
    float s1v = s1g[((size_t)b * TT + t) * K1 + tid];
    float s = bn1_g[tid] * rsqrtf(bn1_v[tid] + EPSV);
    gp[tid] = make_float4(s1v, b1[tid], s, bn1_b[tid] - bn1_m[tid] * s);
  }
  if (tid >= 64 && tid < 64 + NN) r_lds[tid - 64] = rsum[b * NN + (tid - 64)];
  if (tid >= 192 && tid < 192 + K2) {
    int m = tid - 192;
    float s = bn2_g[m] * rsqrtf(bn2_v[m] + EPSV);
    p2[m] = b2[m];
    p2[K2 + m] = s;
    p2[2 * K2 + m] = bn2_b[m] - bn2_m[m] * s;
  }
  __syncthreads();

  f32x4 z4 = {0.f, 0.f, 0.f, 0.f};

  {
    float rj0 = r_lds[(wave * 2 + 0) * 16 + l15];
    float rj1 = r_lds[(wave * 2 + 1) * 16 + l15];
    f32x4 acc[2][2];
    acc[0][0] = z4; acc[0][1] = z4; acc[1][0] = z4; acc[1][1] = z4;
#pragma unroll
    for (int kt = 0; kt < 2; ++kt) {
      float4 gpv[8];
#pragma unroll
      for (int e = 0; e < 8; ++e) gpv[e] = gp[kt * 32 + l4 * 8 + e];
      short8 bfrag0 = *((const short8*)&w2_lds[(0 + l15) * WLD + kt * 32 + l4 * 8]);
      short8 bfrag1 = *((const short8*)&w2_lds[(16 + l15) * WLD + kt * 32 + l4 * 8]);
#pragma unroll
      for (int jt = 0; jt < 2; ++jt) {
        float rj = jt ? rj1 : rj0;
        short8 af;
#pragma unroll
        for (int e = 0; e < 8; ++e) {
          float4 p = gpv[e];
          float v = leaky_(rj * p.x + p.y) * p.z + p.w;
          af[e] = (short)f2bf(v);
        }
        acc[jt][0] = __builtin_amdgcn_mfma_f32_16x16x32_bf16(af, bfrag0, acc[jt][0], 0, 0, 0);
        acc[jt][1] = __builtin_amdgcn_mfma_f32_16x16x32_bf16(af, bfrag1, acc[jt][1], 0, 0, 0);
      }
    }
#pragma unroll
    for (int jt = 0; jt < 2; ++jt) {
      int jbase = (wave * 2 + jt) * 16 + l4 * 4;
#pragma unroll
      for (int mt = 0; mt < 2; ++mt) {
        int m = mt * 16 + l15;
        unsigned lo = (unsigned)f2bf(acc[jt][mt][0]) | ((unsigned)f2bf(acc[jt][mt][1]) << 16);
        unsigned hi = (unsigned)f2bf(acc[jt][mt][2]) | ((unsigned)f2bf(acc[jt][mt][3]) << 16);
        uint2 val; val.x = lo; val.y = hi;
        *((uint2*)&s2_lds[m * SLD + jbase]) = val;
      }
    }
  }
  __syncthreads();

  float c0 = 0.f, c1 = 0.f, c2 = 0.f;
  {
    f32x4 acc[2][2];
    acc[0][0] = z4; acc[0][1] = z4; acc[1][0] = z4; acc[1][1] = z4;
#pragma unroll
    for (int kt = 0; kt < 4; ++kt) {
      short8 bfrag0 = *((const short8*)&s2_lds[(0 + l15) * SLD + kt * 32 + l4 * 8]);
      short8 bfrag1 = *((const short8*)&s2_lds[(16 + l15) * SLD + kt * 32 + l4 * 8]);
#pragma unroll
      for (int it = 0; it < 2; ++it) {
        int i = (wave * 2 + it) * 16 + l15;
        short8 afrag = *((const short8*)&a_lds[i * ALD + kt * 32 + l4 * 8]);
        acc[it][0] = __builtin_amdgcn_mfma_f32_16x16x32_bf16(afrag, bfrag0, acc[it][0], 0, 0, 0);
        acc[it][1] = __builtin_amdgcn_mfma_f32_16x16x32_bf16(afrag, bfrag1, acc[it][1], 0, 0, 0);
      }
    }
    float gv[2][2][4];
#pragma unroll
    for (int it = 0; it < 2; ++it)
#pragma unroll
      for (int mt = 0; mt < 2; ++mt) {
        int m = mt * 16 + l15;
        float bb = p2[m], bs = p2[K2 + m], bo = p2[2 * K2 + m];
#pragma unroll
        for (int r = 0; r < 4; ++r) gv[it][mt][r] = leaky_(acc[it][mt][r] + bb) * bs + bo;
      }
#pragma unroll
    for (int g = 0; g < 4; ++g) {
      int it = g >> 1, mt = g & 1;
      float4 v0 = d1r[(((size_t)t * 4 + g) * 3 + 0) * 256 + tid];
      float4 v1 = d1r[(((size_t)t * 4 + g) * 3 + 1) * 256 + tid];
      float4 v2 = d1r[(((size_t)t * 4 + g) * 3 + 2) * 256 + tid];
      c0 += gv[it][mt][0] * v0.x + gv[it][mt][1] * v0.y + gv[it][mt][2] * v0.z + gv[it][mt][3] * v0.w;
      c1 += gv[it][mt][0] * v1.x + gv[it][mt][1] * v1.y + gv[it][mt][2] * v1.z + gv[it][mt][3] * v1.w;
      c2 += gv[it][mt][0] * v2.x + gv[it][mt][1] * v2.y + gv[it][mt][2] * v2.z + gv[it][mt][3] * v2.w;
    }
  }
#pragma unroll
  for (int off = 32; off >= 1; off >>= 1) {
    c0 += __shfl_down(c0, off);
    c1 += __shfl_down(c1, off);
    c2 += __shfl_down(c2, off);
  }
  if (lane == 0) { red[wave * 3 + 0] = c0; red[wave * 3 + 1] = c1; red[wave * 3 + 2] = c2; }
  __syncthreads();
  if (tid == 0) {
    float s0 = 0.f, s1v = 0.f, s2v = 0.f;
    for (int w = 0; w < 4; ++w) { s0 += red[w * 3]; s1v += red[w * 3 + 1]; s2v += red[w * 3 + 2]; }
    part[((size_t)b * TT + t) * 3 + 0] = s0;
    part[((size_t)b * TT + t) * 3 + 1] = s1v;
    part[((size_t)b * TT + t) * 3 + 2] = s2v;
  }
}

// ---------------- final: reduce partials over t, relu, d2 ----------------
__global__ __launch_bounds__(128) void k_out(const float* __restrict__ part,
                                             const float* __restrict__ d1b,
                                             const float* __restrict__ d2w,
                                             const float* __restrict__ d2b,
                                             float* __restrict__ out) {
  int b = blockIdx.x, n = threadIdx.x;
  float s[3] = {0.f, 0.f, 0.f};
  const float* p = part + (size_t)b * TT * 3;
  for (int t = 0; t < TT; ++t) {
    s[0] += p[t * 3];
    s[1] += p[t * 3 + 1];
    s[2] += p[t * 3 + 2];
  }
  float o = d2b[n];
#pragma unroll
  for (int c = 0; c < 3; ++c) {
    float d = s[c] + d1b[c];
    d = d > 0.f ? d : 0.f;
    o += d * d2w[c * NN + n];
  }
  out[b * NN + n] = o;
}

extern "C" void kernel_launch(void* const* d_in, const int* in_sizes, int n_in,
                              void* d_out, int out_size, void* d_ws, size_t ws_size,
                              hipStream_t stream) {
  const float* x      = (const float*)d_in[0];
  const float* a      = (const float*)d_in[1];
  const float* lstm_k = (const float*)d_in[2];
  const float* lstm_r = (const float*)d_in[3];
  const float* lstm_b = (const float*)d_in[4];
  const float* bnl_g  = (const float*)d_in[5];
  const float* bnl_b  = (const float*)d_in[6];
  const float* bnl_m  = (const float*)d_in[7];
  const float* bnl_v  = (const float*)d_in[8];
  const float* w1     = (const float*)d_in[9];
  const float* b1     = (const float*)d_in[10];
  const float* bn1_g  = (const float*)d_in[11];
  const float* bn1_b  = (const float*)d_in[12];
  const float* bn1_m  = (const float*)d_in[13];
  const float* bn1_v  = (const float*)d_in[14];
  const float* w2     = (const float*)d_in[15];
  const float* b2     = (const float*)d_in[16];
  const float* bn2_g  = (const float*)d_in[17];
  const float* bn2_b  = (const float*)d_in[18];
  const float* bn2_m  = (const float*)d_in[19];
  const float* bn2_v  = (const float*)d_in[20];
  const float* d1_w   = (const float*)d_in[21];
  const float* d1_b   = (const float*)d_in[22];
  const float* d2_w   = (const float*)d_in[23];
  const float* d2_b   = (const float*)d_in[24];
  float* out = (float*)d_out;

  char* ws = (char*)d_ws;
  float* xz            = (float*)(ws + 0);                 // 2,097,152 B
  float* s1            = (float*)(ws + 2097152);           //   524,288 B
  float* rsum          = (float*)(ws + 2621440);           //    16,384 B
  float* part          = (float*)(ws + 2637824);           //    24,576 B
  unsigned short* apad = (unsigned short*)(ws + 2662400);  // 1,114,112 B
  unsigned short* w2t  = (unsigned short*)(ws + 3776512);  //     4,608 B
  unsigned* wrp        = (unsigned*)(ws + 3781120);        //    32,768 B
  unsigned* w1p        = (unsigned*)(ws + 3813888);        //     8,192 B
  float4* d1r          = (float4*)(ws + 3822080);          // 3,145,728 B

  k_pre<<<352, 256, 0, stream>>>(x, lstm_k, lstm_b, a, w2, lstm_r, w1, d1_w,
                                 xz, rsum, apad, w2t, wrp, w1p, d1r);
  k_lstm<<<4, 512, 0, stream>>>(xz, wrp, w1p, bnl_g, bnl_b, bnl_m, bnl_v, s1);
  k_gcn<<<BB * TT, 256, 0, stream>>>(s1, rsum, apad, w2t, b1, bn1_g, bn1_b, bn1_m, bn1_v,
                                     b2, bn2_g, bn2_b, bn2_m, bn2_v, d1r, part);
  k_out<<<BB, 128, 0, stream>>>(part, d1_b, d2_w, d2_b, out);
}

// Round 11
// 101.754 us; speedup vs baseline: 1.1531x; 1.1531x over previous
//
#include <hip/hip_runtime.h>

#define BB 32
#define TT 64
#define NN 128
#define FF 128
#define UU 64
#define K1 64
#define K2 32
#define G4 256
#define EPSV 1e-3f
#define SLOPE 0.01f

#define ALD 136   // a row stride in bf16 elems (128 + 8 pad)
#define SLD 136   // sup2T row stride
#define WLD 72    // w2T row stride

typedef __attribute__((ext_vector_type(8))) short short8;
typedef __attribute__((ext_vector_type(4))) float f32x4;
typedef __attribute__((ext_vector_type(2))) __fp16 half2v;

__device__ __forceinline__ float sigmoidf_(float x) {
  return __builtin_amdgcn_rcpf(1.f + __expf(-x));
}
__device__ __forceinline__ float tanhf_(float x) {
  return 1.f - 2.f * __builtin_amdgcn_rcpf(__expf(2.f * x) + 1.f);
}
__device__ __forceinline__ float leaky_(float x) { return x >= 0.f ? x : SLOPE * x; }
__device__ __forceinline__ unsigned short f2bf(float x) {
  union { float f; unsigned u; } v; v.f = x;
  unsigned r = v.u + 0x7fff + ((v.u >> 16) & 1);
  return (unsigned short)(r >> 16);
}

// ---- prep (0..31) + xz GEMM (32..287) + d1w reorder via LDS transpose (288..351) ----
__global__ __launch_bounds__(256) void k_pre(const float* __restrict__ x,
                                             const float* __restrict__ wk,
                                             const float* __restrict__ bias,
                                             const float* __restrict__ a,
                                             const float* __restrict__ w2,
                                             const float* __restrict__ wr,
                                             const float* __restrict__ w1,
                                             const float* __restrict__ d1w,
                                             float* __restrict__ xz,
                                             float* __restrict__ rsum,
                                             unsigned short* __restrict__ apad,
                                             unsigned short* __restrict__ w2t,
                                             unsigned* __restrict__ wrp,
                                             unsigned* __restrict__ w1p,
                                             float4* __restrict__ d1r) {
  int tid = threadIdx.x;
  if (blockIdx.x < 32) {
    int b = blockIdx.x;
    int wave = tid >> 6, lane = tid & 63;
    const float* ab = a + (size_t)b * NN * NN;
    for (int r = 0; r < 32; ++r) {
      int row = wave * 32 + r;
      float2 v = *(const float2*)(ab + (size_t)row * NN + lane * 2);
      float s = v.x + v.y;
#pragma unroll
      for (int off = 32; off >= 1; off >>= 1) s += __shfl_down(s, off);
      if (lane == 0) rsum[b * NN + row] = s;
    }
    unsigned short* ap = apad + (size_t)b * NN * ALD;
    for (int idx = tid; idx < NN * NN; idx += 256) {
      int i = idx >> 7, j = idx & 127;
      ap[i * ALD + j] = f2bf(ab[idx]);
    }
    if (b == 0) {
      for (int idx = tid; idx < K1 * K2; idx += 256) {
        int k = idx >> 5, m = idx & 31;
        w2t[m * WLD + k] = f2bf(w2[idx]);
      }
    }
    if (b == 1) {
      // pack Wr f16x2, LANE-CONTIGUOUS: wrp[u*128 + gate*32 + p]
      for (int idx = tid; idx < 4 * 32 * UU; idx += 256) {
        int p = idx & 31;
        int gate = (idx >> 5) & 3;
        int u = idx >> 7;
        int col = gate * UU + u;
        union { __fp16 h[2]; unsigned u; } pk;
        pk.h[0] = (__fp16)wr[(2 * p) * G4 + col];
        pk.h[1] = (__fp16)wr[(2 * p + 1) * G4 + col];
        wrp[idx] = pk.u;
      }
    }
    if (b == 2) {
      // pack w1 f16x2, LANE-CONTIGUOUS: w1p[k*32 + p]
      for (int idx = tid; idx < 32 * K1; idx += 256) {
        int p = idx & 31, k = idx >> 5;
        union { __fp16 h[2]; unsigned u; } pk;
        pk.h[0] = (__fp16)w1[(2 * p) * K1 + k];
        pk.h[1] = (__fp16)w1[(2 * p + 1) * K1 + k];
        w1p[idx] = pk.u;
      }
    }
  } else if (blockIdx.x < 288) {
    __shared__ float xs[8][FF];
    int row0 = (blockIdx.x - 32) * 8;
    for (int i = tid; i < 8 * FF; i += 256) xs[i >> 7][i & 127] = x[(size_t)row0 * FF + i];
    __syncthreads();
    int g = tid;
    float acc[8];
    float bg = bias[g];
#pragma unroll
    for (int r = 0; r < 8; ++r) acc[r] = bg;
    for (int f = 0; f < FF; ++f) {
      float w = wk[f * G4 + g];
#pragma unroll
      for (int r = 0; r < 8; ++r) acc[r] += xs[r][f] * w;
    }
#pragma unroll
    for (int r = 0; r < 8; ++r) xz[(size_t)(row0 + r) * G4 + g] = acc[r];
  } else {
    // d1w -> d1r (MFMA C-fragment order) via LDS transpose; block = t, 4 chunks of 32 rows
    int t = blockIdx.x - 288;
    __shared__ float dt[3072];  // 12 KB: 32 rows x 32 m x 3 c
    const float* src = d1w + (size_t)t * NN * K2 * 3;
    for (int c32 = 0; c32 < 4; ++c32) {
      __syncthreads();  // protect previous chunk's reads
      for (int i = tid; i < 768; i += 256)
        ((float4*)dt)[i] = ((const float4*)(src + c32 * 3072))[i];
      __syncthreads();
#pragma unroll
      for (int q = 0; q < 3; ++q) {
        int item = q * 256 + tid;
        int l = item & 63;
        int gc = item >> 6;          // 0..11
        int g = gc / 3, c = gc % 3;
        int it = g >> 1, mt = g & 1;
        int l15v = l & 15, l4v = l >> 4;
        int m = mt * 16 + l15v;
        int rowbase = it * 16 + l4v * 4;
        float4 v;
        v.x = dt[(rowbase + 0) * 96 + m * 3 + c];
        v.y = dt[(rowbase + 1) * 96 + m * 3 + c];
        v.z = dt[(rowbase + 2) * 96 + m * 3 + c];
        v.w = dt[(rowbase + 3) * 96 + m * 3 + c];
        d1r[(((size_t)t * 4 + g) * 3 + c) * 256 + c32 * 64 + l] = v;
      }
    }
  }
}

// ---------------- LSTM scan: 4 batches/block, 2 waves/batch, 2 waves per SIMD ----------------
// wave pair (2p, 2p+1) = batch p: role 0 computes gates (i,f), role 1 computes (g,o).
// Each lane holds only 64 weight dwords (no spill). z exchanged via parity-dbuf LDS,
// ONE barrier/step; c,h computed redundantly by both roles; each wave keeps a private
// h16 copy (in-order LDS pipe, no extra barrier). amdgpu_waves_per_eu(2,2) pins the
// allocator at 1 block/CU so the weight arrays stay register-resident.
__global__ __launch_bounds__(512)
__attribute__((amdgpu_waves_per_eu(2, 2)))
void k_lstm(const float* __restrict__ xz,
            const unsigned* __restrict__ wrp,
            const unsigned* __restrict__ w1p,
            const float* __restrict__ bnl_g,
            const float* __restrict__ bnl_b,
            const float* __restrict__ bnl_m,
            const float* __restrict__ bnl_v,
            float* __restrict__ s1out) {
  __shared__ float zex[2][4][2][2 * UU];          // parity/batch/role/(2 gates x 64) : 8 KB
  __shared__ __align__(16) __fp16 h16[8][UU];     // per-WAVE private h copy : 1 KB
  __shared__ __align__(16) __fp16 hist[4][TT * UU];  // bn'd h history per batch : 32 KB
  int tid = threadIdx.x;
  int wave = tid >> 6, lane = tid & 63;
  int pb = wave >> 1;        // batch within block
  int role = wave & 1;       // 0: gates i,f ; 1: gates g,o
  int b = blockIdx.x * 4 + pb;

  // weights: contiguous 64 dwords = wrp[lane*128 + role*64 ...] -> 16 dwordx4 loads
  unsigned wv0[32], wv1[32];
  {
    const uint4* wp = (const uint4*)(wrp + (size_t)lane * 128 + role * 64);
#pragma unroll
    for (int k = 0; k < 8; ++k) {
      uint4 v = wp[k];
      wv0[4 * k + 0] = v.x; wv0[4 * k + 1] = v.y; wv0[4 * k + 2] = v.z; wv0[4 * k + 3] = v.w;
    }
#pragma unroll
    for (int k = 0; k < 8; ++k) {
      uint4 v = wp[8 + k];
      wv1[4 * k + 0] = v.x; wv1[4 * k + 1] = v.y; wv1[4 * k + 2] = v.z; wv1[4 * k + 3] = v.w;
    }
  }
  float bscale = bnl_g[lane] * rsqrtf(bnl_v[lane] + EPSV);
  float boff = bnl_b[lane] - bnl_m[lane] * bscale;
  h16[wave][lane] = (__fp16)0.f;
  float c = 0.f;

  const float* xzb = xz + (size_t)b * TT * G4;
  // this wave's two xz gate-columns: role*128 + lane, role*128 + 64 + lane
  float cz0 = xzb[role * 128 + lane];
  float cz1 = xzb[role * 128 + 64 + lane];
  __syncthreads();

  for (int t = 0; t < TT; ++t) {
    int tn = (t + 1 < TT) ? t + 1 : t;
    float nz0 = xzb[tn * G4 + role * 128 + lane];        // prefetch, used next iter
    float nz1 = xzb[tn * G4 + role * 128 + 64 + lane];
    // read own h16 copy (wave-private, uniform-addr b128 reads)
    unsigned hw[32];
    {
      const uint4* hq = (const uint4*)&h16[wave][0];
#pragma unroll
      for (int k = 0; k < 8; ++k) {
        uint4 v = hq[k];
        hw[4 * k + 0] = v.x; hw[4 * k + 1] = v.y; hw[4 * k + 2] = v.z; hw[4 * k + 3] = v.w;
      }
    }
    float z0 = cz0, z1 = cz1;
#pragma unroll
    for (int p = 0; p < 32; ++p) {
      half2v hh = __builtin_bit_cast(half2v, hw[p]);
      z0 = __builtin_amdgcn_fdot2(__builtin_bit_cast(half2v, wv0[p]), hh, z0, false);
      z1 = __builtin_amdgcn_fdot2(__builtin_bit_cast(half2v, wv1[p]), hh, z1, false);
    }
    int par = t & 1;
    zex[par][pb][role][lane] = z0;
    zex[par][pb][role][UU + lane] = z1;
    __syncthreads();   // the only barrier per step
    float pz0 = zex[par][pb][role ^ 1][lane];
    float pz1 = zex[par][pb][role ^ 1][UU + lane];
    float zi = role ? pz0 : z0;
    float zf = role ? pz1 : z1;
    float zg = role ? z0 : pz0;
    float zo = role ? z1 : pz1;
    float i_ = sigmoidf_(zi), f_ = sigmoidf_(zf), g_ = tanhf_(zg), o_ = sigmoidf_(zo);
    c = f_ * c + i_ * g_;
    float h = o_ * tanhf_(c);
    h16[wave][lane] = (__fp16)h;                       // own copy, in-order LDS pipe
    if (role == 0) hist[pb][t * UU + lane] = (__fp16)(h * bscale + boff);
    cz0 = nz0; cz1 = nz1;
  }
  __syncthreads();

  // s1 tail: wave handles 32 rows of its batch (role picks the half); lane = column k
  unsigned w1v[32];
  {
    const uint4* wp1 = (const uint4*)(w1p + (size_t)lane * 32);
#pragma unroll
    for (int k = 0; k < 8; ++k) {
      uint4 v = wp1[k];
      w1v[4 * k + 0] = v.x; w1v[4 * k + 1] = v.y; w1v[4 * k + 2] = v.z; w1v[4 * k + 3] = v.w;
    }
  }
  float* s1b = s1out + (size_t)b * TT * K1;
  for (int r = 0; r < 32; ++r) {
    int t = role * 32 + r;
    unsigned hw2[32];
    {
      const uint4* hq = (const uint4*)(&hist[pb][0] + t * UU);
#pragma unroll
      for (int k = 0; k < 8; ++k) {
        uint4 v = hq[k];
        hw2[4 * k + 0] = v.x; hw2[4 * k + 1] = v.y; hw2[4 * k + 2] = v.z; hw2[4 * k + 3] = v.w;
      }
    }
    float acc = 0.f;
#pragma unroll
    for (int p = 0; p < 32; ++p)
      acc = __builtin_amdgcn_fdot2(__builtin_bit_cast(half2v, w1v[p]),
                                   __builtin_bit_cast(half2v, hw2[p]), acc, false);
    s1b[t * K1 + lane] = acc;
  }
}

// ---------------- fused GCN1+GCN2+d1 partial, one block per (t,b), t-major ----------------
__global__ __launch_bounds__(256) void k_gcn(
    const float* __restrict__ s1g, const float* __restrict__ rsum,
    const unsigned short* __restrict__ apad, const unsigned short* __restrict__ w2t,
    const float* __restrict__ b1,
    const float* __restrict__ bn1_g, const float* __restrict__ bn1_b,
    const float* __restrict__ bn1_m, const float* __restrict__ bn1_v,
    const float* __restrict__ b2,
    const float* __restrict__ bn2_g, const float* __restrict__ bn2_b,
    const float* __restrict__ bn2_m, const float* __restrict__ bn2_v,
    const float4* __restrict__ d1r, float* __restrict__ part) {
  __shared__ unsigned short a_lds[NN * ALD];
  __shared__ unsigned short s2_lds[K2 * SLD];
  __shared__ unsigned short w2_lds[K2 * WLD];
  __shared__ float4 gp[K1];
  __shared__ float r_lds[NN];
  __shared__ float p2[3 * K2];
  __shared__ float red[12];

  int blk = blockIdx.x;
  int b = blk & 31, t = blk >> 5;   // t-major
  int tid = threadIdx.x;
  int lane = tid & 63, wave = tid >> 6;
  int l15 = lane & 15, l4 = lane >> 4;

  {
    const uint4* src = (const uint4*)(apad + (size_t)b * NN * ALD);
    uint4* dst = (uint4*)a_lds;
    for (int i = tid; i < NN * ALD / 8; i += 256) dst[i] = src[i];
  }
  {
    const uint2* src = (const uint2*)w2t;
    uint2* dst = (uint2*)w2_lds;
    for (int i = tid; i < K2 * WLD / 4; i += 256) dst[i] = src[i];
  }
  if (tid < K1) {
    float s1v = s1g[((size_t)b * TT + t) * K1 + tid];
    float s = bn1_g[tid] * rsqrtf(bn1_v[tid] + EPSV);
    gp[tid] = make_float4(s1v, b1[tid], s, bn1_b[tid] - bn1_m[tid] * s);
  }
  if (tid >= 64 && tid < 64 + NN) r_lds[tid - 64] = rsum[b * NN + (tid - 64)];
  if (tid >= 192 && tid < 192 + K2) {
    int m = tid - 192;
    float s = bn2_g[m] * rsqrtf(bn2_v[m] + EPSV);
    p2[m] = b2[m];
    p2[K2 + m] = s;
    p2[2 * K2 + m] = bn2_b[m] - bn2_m[m] * s;
  }
  __syncthreads();

  f32x4 z4 = {0.f, 0.f, 0.f, 0.f};

  {
    float rj0 = r_lds[(wave * 2 + 0) * 16 + l15];
    float rj1 = r_lds[(wave * 2 + 1) * 16 + l15];
    f32x4 acc[2][2];
    acc[0][0] = z4; acc[0][1] = z4; acc[1][0] = z4; acc[1][1] = z4;
#pragma unroll
    for (int kt = 0; kt < 2; ++kt) {
      float4 gpv[8];
#pragma unroll
      for (int e = 0; e < 8; ++e) gpv[e] = gp[kt * 32 + l4 * 8 + e];
      short8 bfrag0 = *((const short8*)&w2_lds[(0 + l15) * WLD + kt * 32 + l4 * 8]);
      short8 bfrag1 = *((const short8*)&w2_lds[(16 + l15) * WLD + kt * 32 + l4 * 8]);
#pragma unroll
      for (int jt = 0; jt < 2; ++jt) {
        float rj = jt ? rj1 : rj0;
        short8 af;
#pragma unroll
        for (int e = 0; e < 8; ++e) {
          float4 p = gpv[e];
          float v = leaky_(rj * p.x + p.y) * p.z + p.w;
          af[e] = (short)f2bf(v);
        }
        acc[jt][0] = __builtin_amdgcn_mfma_f32_16x16x32_bf16(af, bfrag0, acc[jt][0], 0, 0, 0);
        acc[jt][1] = __builtin_amdgcn_mfma_f32_16x16x32_bf16(af, bfrag1, acc[jt][1], 0, 0, 0);
      }
    }
#pragma unroll
    for (int jt = 0; jt < 2; ++jt) {
      int jbase = (wave * 2 + jt) * 16 + l4 * 4;
#pragma unroll
      for (int mt = 0; mt < 2; ++mt) {
        int m = mt * 16 + l15;
        unsigned lo = (unsigned)f2bf(acc[jt][mt][0]) | ((unsigned)f2bf(acc[jt][mt][1]) << 16);
        unsigned hi = (unsigned)f2bf(acc[jt][mt][2]) | ((unsigned)f2bf(acc[jt][mt][3]) << 16);
        uint2 val; val.x = lo; val.y = hi;
        *((uint2*)&s2_lds[m * SLD + jbase]) = val;
      }
    }
  }
  __syncthreads();

  float c0 = 0.f, c1 = 0.f, c2 = 0.f;
  {
    f32x4 acc[2][2];
    acc[0][0] = z4; acc[0][1] = z4; acc[1][0] = z4; acc[1][1] = z4;
#pragma unroll
    for (int kt = 0; kt < 4; ++kt) {
      short8 bfrag0 = *((const short8*)&s2_lds[(0 + l15) * SLD + kt * 32 + l4 * 8]);
      short8 bfrag1 = *((const short8*)&s2_lds[(16 + l15) * SLD + kt * 32 + l4 * 8]);
#pragma unroll
      for (int it = 0; it < 2; ++it) {
        int i = (wave * 2 + it) * 16 + l15;
        short8 afrag = *((const short8*)&a_lds[i * ALD + kt * 32 + l4 * 8]);
        acc[it][0] = __builtin_amdgcn_mfma_f32_16x16x32_bf16(afrag, bfrag0, acc[it][0], 0, 0, 0);
        acc[it][1] = __builtin_amdgcn_mfma_f32_16x16x32_bf16(afrag, bfrag1, acc[it][1], 0, 0, 0);
      }
    }
    float gv[2][2][4];
#pragma unroll
    for (int it = 0; it < 2; ++it)
#pragma unroll
      for (int mt = 0; mt < 2; ++mt) {
        int m = mt * 16 + l15;
        float bb = p2[m], bs = p2[K2 + m], bo = p2[2 * K2 + m];
#pragma unroll
        for (int r = 0; r < 4; ++r) gv[it][mt][r] = leaky_(acc[it][mt][r] + bb) * bs + bo;
      }
#pragma unroll
    for (int g = 0; g < 4; ++g) {
      int it = g >> 1, mt = g & 1;
      float4 v0 = d1r[(((size_t)t * 4 + g) * 3 + 0) * 256 + tid];
      float4 v1 = d1r[(((size_t)t * 4 + g) * 3 + 1) * 256 + tid];
      float4 v2 = d1r[(((size_t)t * 4 + g) * 3 + 2) * 256 + tid];
      c0 += gv[it][mt][0] * v0.x + gv[it][mt][1] * v0.y + gv[it][mt][2] * v0.z + gv[it][mt][3] * v0.w;
      c1 += gv[it][mt][0] * v1.x + gv[it][mt][1] * v1.y + gv[it][mt][2] * v1.z + gv[it][mt][3] * v1.w;
      c2 += gv[it][mt][0] * v2.x + gv[it][mt][1] * v2.y + gv[it][mt][2] * v2.z + gv[it][mt][3] * v2.w;
    }
  }
#pragma unroll
  for (int off = 32; off >= 1; off >>= 1) {
    c0 += __shfl_down(c0, off);
    c1 += __shfl_down(c1, off);
    c2 += __shfl_down(c2, off);
  }
  if (lane == 0) { red[wave * 3 + 0] = c0; red[wave * 3 + 1] = c1; red[wave * 3 + 2] = c2; }
  __syncthreads();
  if (tid == 0) {
    float s0 = 0.f, s1v = 0.f, s2v = 0.f;
    for (int w = 0; w < 4; ++w) { s0 += red[w * 3]; s1v += red[w * 3 + 1]; s2v += red[w * 3 + 2]; }
    part[((size_t)b * TT + t) * 3 + 0] = s0;
    part[((size_t)b * TT + t) * 3 + 1] = s1v;
    part[((size_t)b * TT + t) * 3 + 2] = s2v;
  }
}

// ---------------- final: reduce partials over t, relu, d2 ----------------
__global__ __launch_bounds__(128) void k_out(const float* __restrict__ part,
                                             const float* __restrict__ d1b,
                                             const float* __restrict__ d2w,
                                             const float* __restrict__ d2b,
                                             float* __restrict__ out) {
  int b = blockIdx.x, n = threadIdx.x;
  float s[3] = {0.f, 0.f, 0.f};
  const float* p = part + (size_t)b * TT * 3;
  for (int t = 0; t < TT; ++t) {
    s[0] += p[t * 3];
    s[1] += p[t * 3 + 1];
    s[2] += p[t * 3 + 2];
  }
  float o = d2b[n];
#pragma unroll
  for (int c = 0; c < 3; ++c) {
    float d = s[c] + d1b[c];
    d = d > 0.f ? d : 0.f;
    o += d * d2w[c * NN + n];
  }
  out[b * NN + n] = o;
}

extern "C" void kernel_launch(void* const* d_in, const int* in_sizes, int n_in,
                              void* d_out, int out_size, void* d_ws, size_t ws_size,
                              hipStream_t stream) {
  const float* x      = (const float*)d_in[0];
  const float* a      = (const float*)d_in[1];
  const float* lstm_k = (const float*)d_in[2];
  const float* lstm_r = (const float*)d_in[3];
  const float* lstm_b = (const float*)d_in[4];
  const float* bnl_g  = (const float*)d_in[5];
  const float* bnl_b  = (const float*)d_in[6];
  const float* bnl_m  = (const float*)d_in[7];
  const float* bnl_v  = (const float*)d_in[8];
  const float* w1     = (const float*)d_in[9];
  const float* b1     = (const float*)d_in[10];
  const float* bn1_g  = (const float*)d_in[11];
  const float* bn1_b  = (const float*)d_in[12];
  const float* bn1_m  = (const float*)d_in[13];
  const float* bn1_v  = (const float*)d_in[14];
  const float* w2     = (const float*)d_in[15];
  const float* b2     = (const float*)d_in[16];
  const float* bn2_g  = (const float*)d_in[17];
  const float* bn2_b  = (const float*)d_in[18];
  const float* bn2_m  = (const float*)d_in[19];
  const float* bn2_v  = (const float*)d_in[20];
  const float* d1_w   = (const float*)d_in[21];
  const float* d1_b   = (const float*)d_in[22];
  const float* d2_w   = (const float*)d_in[23];
  const float* d2_b   = (const float*)d_in[24];
  float* out = (float*)d_out;

  char* ws = (char*)d_ws;
  float* xz            = (float*)(ws + 0);                 // 2,097,152 B
  float* s1            = (float*)(ws + 2097152);           //   524,288 B
  float* rsum          = (float*)(ws + 2621440);           //    16,384 B
  float* part          = (float*)(ws + 2637824);           //    24,576 B
  unsigned short* apad = (unsigned short*)(ws + 2662400);  // 1,114,112 B
  unsigned short* w2t  = (unsigned short*)(ws + 3776512);  //     4,608 B
  unsigned* wrp        = (unsigned*)(ws + 3781120);        //    32,768 B
  unsigned* w1p        = (unsigned*)(ws + 3813888);        //     8,192 B
  float4* d1r          = (float4*)(ws + 3822080);          // 3,145,728 B

  k_pre<<<352, 256, 0, stream>>>(x, lstm_k, lstm_b, a, w2, lstm_r, w1, d1_w,
                                 xz, rsum, apad, w2t, wrp, w1p, d1r);
  k_lstm<<<8, 512, 0, stream>>>(xz, wrp, w1p, bnl_g, bnl_b, bnl_m, bnl_v, s1);
  k_gcn<<<BB * TT, 256, 0, stream>>>(s1, rsum, apad, w2t, b1, bn1_g, bn1_b, bn1_m, bn1_v,
                                     b2, bn2_g, bn2_b, bn2_m, bn2_v, d1r, part);
  k_out<<<BB, 128, 0, stream>>>(part, d1_b, d2_w, d2_b, out);
}

// Round 12
// 72.305 us; speedup vs baseline: 1.6228x; 1.4073x over previous
//
#include <hip/hip_runtime.h>

#define BB 32
#define TT 64
#define NN 128
#define FF 128
#define UU 64
#define K1 64
#define K2 32
#define G4 256
#define EPSV 1e-3f
#define SLOPE 0.01f

#define ALD 136
#define SLD 136
#define WLD 72

typedef __attribute__((ext_vector_type(8))) short short8;
typedef __attribute__((ext_vector_type(4))) float f32x4;
typedef __attribute__((ext_vector_type(2))) __fp16 half2v;

__device__ __forceinline__ float sigmoidf_(float x) {
  return __builtin_amdgcn_rcpf(1.f + __expf(-x));
}
__device__ __forceinline__ float tanhf_(float x) {
  return 1.f - 2.f * __builtin_amdgcn_rcpf(__expf(2.f * x) + 1.f);
}
__device__ __forceinline__ float leaky_(float x) { return x >= 0.f ? x : SLOPE * x; }
__device__ __forceinline__ unsigned short f2bf(float x) {
  union { float f; unsigned u; } v; v.f = x;
  unsigned r = v.u + 0x7fff + ((v.u >> 16) & 1);
  return (unsigned short)(r >> 16);
}

// ---------------- K1: xz GEMM (blocks 0..255) + weight packing (256,257) ----------------
__global__ __launch_bounds__(256) void k_xzp(const float* __restrict__ x,
                                             const float* __restrict__ wk,
                                             const float* __restrict__ bias,
                                             const float* __restrict__ wr,
                                             const float* __restrict__ w1,
                                             float* __restrict__ xz,
                                             unsigned* __restrict__ wrp,
                                             unsigned* __restrict__ w1p) {
  int tid = threadIdx.x;
  if (blockIdx.x < 256) {
    __shared__ float xs[8][FF];
    int row0 = blockIdx.x * 8;
    for (int i = tid; i < 8 * FF; i += 256) xs[i >> 7][i & 127] = x[(size_t)row0 * FF + i];
    __syncthreads();
    int g = tid;
    float acc[8];
    float bg = bias[g];
#pragma unroll
    for (int r = 0; r < 8; ++r) acc[r] = bg;
    for (int f = 0; f < FF; ++f) {
      float w = wk[f * G4 + g];
#pragma unroll
      for (int r = 0; r < 8; ++r) acc[r] += xs[r][f] * w;
    }
#pragma unroll
    for (int r = 0; r < 8; ++r) xz[(size_t)(row0 + r) * G4 + g] = acc[r];
  } else if (blockIdx.x == 256) {
    // pack Wr f16x2, lane-contiguous: wrp[u*128 + gate*32 + p]
    for (int idx = tid; idx < 4 * 32 * UU; idx += 256) {
      int p = idx & 31;
      int gate = (idx >> 5) & 3;
      int u = idx >> 7;
      int col = gate * UU + u;
      union { __fp16 h[2]; unsigned u; } pk;
      pk.h[0] = (__fp16)wr[(2 * p) * G4 + col];
      pk.h[1] = (__fp16)wr[(2 * p + 1) * G4 + col];
      wrp[idx] = pk.u;
    }
  } else {
    // pack w1 f16x2, lane-contiguous: w1p[k*32 + p]
    for (int idx = tid; idx < 32 * K1; idx += 256) {
      int p = idx & 31, k = idx >> 5;
      union { __fp16 h[2]; unsigned u; } pk;
      pk.h[0] = (__fp16)w1[(2 * p) * K1 + k];
      pk.h[1] = (__fp16)w1[(2 * p + 1) * K1 + k];
      w1p[idx] = pk.u;
    }
  }
}

// ---------------- K2 mega: scan (0..31) + prep on idle CUs (32..128) ----------------
// Scan: role-split across waves 0/1 (64 weight dwords each -> no spill at the
// (256,1)-granted budget), z exchange via parity-dbuf LDS, 1 barrier/step,
// global-free loop. Waves 2/3 idle through the loop, join the s1 tail.
// Prep blocks (apad/rowsum/w2t/d1r) run concurrently on other CUs.
__global__ __launch_bounds__(256, 1) void k_mega(
    const float* __restrict__ xz, const unsigned* __restrict__ wrp,
    const unsigned* __restrict__ w1p,
    const float* __restrict__ bnl_g, const float* __restrict__ bnl_b,
    const float* __restrict__ bnl_m, const float* __restrict__ bnl_v,
    const float* __restrict__ a, const float* __restrict__ w2,
    const float* __restrict__ d1w,
    float* __restrict__ s1out, float* __restrict__ rsum,
    unsigned short* __restrict__ apad, unsigned short* __restrict__ w2t,
    float4* __restrict__ d1r) {
  __shared__ __align__(16) char smem[76032];
  int tid = threadIdx.x;
  int blk = blockIdx.x;

  if (blk < 32) {
    float* xz_lds = (float*)smem;                    // 64 KB
    __fp16* hp = (__fp16*)(smem + 65536);            // 8 KB
    float* zex = (float*)(smem + 73728);             // 2 KB: [par][role][128]
    __fp16* h16 = (__fp16*)(smem + 75776);           // 256 B: [wave][64]
    int wave = tid >> 6, lane = tid & 63;
    int role = wave & 1;
    int b = blk;

    {  // cooperative xz stage
      const float4* src = (const float4*)(xz + (size_t)b * TT * G4);
      float4* dst = (float4*)xz_lds;
#pragma unroll
      for (int k = 0; k < 16; ++k) dst[tid + k * 256] = src[tid + k * 256];
    }
    unsigned wv0[32], wv1[32];
    if (wave < 2) {
      const uint4* wp = (const uint4*)(wrp + (size_t)lane * 128 + role * 64);
#pragma unroll
      for (int k = 0; k < 8; ++k) {
        uint4 v = wp[k];
        wv0[4 * k + 0] = v.x; wv0[4 * k + 1] = v.y; wv0[4 * k + 2] = v.z; wv0[4 * k + 3] = v.w;
      }
#pragma unroll
      for (int k = 0; k < 8; ++k) {
        uint4 v = wp[8 + k];
        wv1[4 * k + 0] = v.x; wv1[4 * k + 1] = v.y; wv1[4 * k + 2] = v.z; wv1[4 * k + 3] = v.w;
      }
      h16[wave * UU + lane] = (__fp16)0.f;
    }
    float bscale = bnl_g[lane] * rsqrtf(bnl_v[lane] + EPSV);
    float boff = bnl_b[lane] - bnl_m[lane] * bscale;
    float c = 0.f;
    __syncthreads();   // xz staged, h16 inited

    for (int t = 0; t < TT; ++t) {
      int par = t & 1;
      float z0, z1;
      if (wave < 2) {
        unsigned hw[32];
        const uint4* hq = (const uint4*)(h16 + wave * UU);
#pragma unroll
        for (int k = 0; k < 8; ++k) {
          uint4 v = hq[k];
          hw[4 * k + 0] = v.x; hw[4 * k + 1] = v.y; hw[4 * k + 2] = v.z; hw[4 * k + 3] = v.w;
        }
        z0 = xz_lds[t * G4 + role * 128 + lane];
        z1 = xz_lds[t * G4 + role * 128 + 64 + lane];
#pragma unroll
        for (int p = 0; p < 32; ++p) {
          half2v hh = __builtin_bit_cast(half2v, hw[p]);
          z0 = __builtin_amdgcn_fdot2(__builtin_bit_cast(half2v, wv0[p]), hh, z0, false);
          z1 = __builtin_amdgcn_fdot2(__builtin_bit_cast(half2v, wv1[p]), hh, z1, false);
        }
        zex[(par * 2 + role) * 128 + lane] = z0;
        zex[(par * 2 + role) * 128 + 64 + lane] = z1;
      }
      __syncthreads();   // the only barrier per step (no global ops in flight)
      if (wave < 2) {
        float pz0 = zex[(par * 2 + (role ^ 1)) * 128 + lane];
        float pz1 = zex[(par * 2 + (role ^ 1)) * 128 + 64 + lane];
        float zi = role ? pz0 : z0;
        float zf = role ? pz1 : z1;
        float zg = role ? z0 : pz0;
        float zo = role ? z1 : pz1;
        float i_ = sigmoidf_(zi), f_ = sigmoidf_(zf), g_ = tanhf_(zg), o_ = sigmoidf_(zo);
        c = f_ * c + i_ * g_;
        float h = o_ * tanhf_(c);
        h16[wave * UU + lane] = (__fp16)h;            // wave-private, in-order LDS pipe
        if (role == 0) hp[t * UU + lane] = (__fp16)(h * bscale + boff);
      }
    }
    __syncthreads();   // hp complete

    // s1 tail: all 4 waves, 16 rows each; lane = output column k
    unsigned w1v[32];
    {
      const uint4* wp1 = (const uint4*)(w1p + (size_t)lane * 32);
#pragma unroll
      for (int k = 0; k < 8; ++k) {
        uint4 v = wp1[k];
        w1v[4 * k + 0] = v.x; w1v[4 * k + 1] = v.y; w1v[4 * k + 2] = v.z; w1v[4 * k + 3] = v.w;
      }
    }
    float* s1b = s1out + (size_t)b * TT * K1;
    for (int r = 0; r < 16; ++r) {
      int t = wave * 16 + r;
      unsigned hw2[32];
      const uint4* hq = (const uint4*)(hp + t * UU);
#pragma unroll
      for (int k = 0; k < 8; ++k) {
        uint4 v = hq[k];
        hw2[4 * k + 0] = v.x; hw2[4 * k + 1] = v.y; hw2[4 * k + 2] = v.z; hw2[4 * k + 3] = v.w;
      }
      float acc = 0.f;
#pragma unroll
      for (int p = 0; p < 32; ++p)
        acc = __builtin_amdgcn_fdot2(__builtin_bit_cast(half2v, w1v[p]),
                                     __builtin_bit_cast(half2v, hw2[p]), acc, false);
      s1b[t * K1 + lane] = acc;
    }
  } else if (blk < 64) {
    // rowsum + apad for batch b = blk-32
    int b = blk - 32;
    int wave = tid >> 6, lane = tid & 63;
    const float* ab = a + (size_t)b * NN * NN;
    for (int r = 0; r < 32; ++r) {
      int row = wave * 32 + r;
      float2 v = *(const float2*)(ab + (size_t)row * NN + lane * 2);
      float s = v.x + v.y;
#pragma unroll
      for (int off = 32; off >= 1; off >>= 1) s += __shfl_down(s, off);
      if (lane == 0) rsum[b * NN + row] = s;
    }
    unsigned short* ap = apad + (size_t)b * NN * ALD;
    for (int idx = tid; idx < NN * NN; idx += 256) {
      int i = idx >> 7, j = idx & 127;
      ap[i * ALD + j] = f2bf(ab[idx]);
    }
  } else if (blk == 64) {
    for (int idx = tid; idx < K1 * K2; idx += 256) {
      int k = idx >> 5, m = idx & 31;
      w2t[m * WLD + k] = f2bf(w2[idx]);
    }
  } else {
    // d1w -> d1r (MFMA C-fragment order) via LDS transpose; t = blk-65
    int t = blk - 65;
    float* dt = (float*)smem;  // 12 KB
    const float* src = d1w + (size_t)t * NN * K2 * 3;
    for (int c32 = 0; c32 < 4; ++c32) {
      __syncthreads();
      for (int i = tid; i < 768; i += 256)
        ((float4*)dt)[i] = ((const float4*)(src + c32 * 3072))[i];
      __syncthreads();
#pragma unroll
      for (int q = 0; q < 3; ++q) {
        int item = q * 256 + tid;
        int l = item & 63;
        int gc = item >> 6;
        int g = gc / 3, cc = gc % 3;
        int it = g >> 1, mt = g & 1;
        int l15v = l & 15, l4v = l >> 4;
        int m = mt * 16 + l15v;
        int rowbase = it * 16 + l4v * 4;
        float4 v;
        v.x = dt[(rowbase + 0) * 96 + m * 3 + cc];
        v.y = dt[(rowbase + 1) * 96 + m * 3 + cc];
        v.z = dt[(rowbase + 2) * 96 + m * 3 + cc];
        v.w = dt[(rowbase + 3) * 96 + m * 3 + cc];
        d1r[(((size_t)t * 4 + g) * 3 + cc) * 256 + c32 * 64 + l] = v;
      }
    }
  }
}

// ---------------- fused GCN1+GCN2+d1 partial, one block per (t,b), t-major ----------------
__global__ __launch_bounds__(256) void k_gcn(
    const float* __restrict__ s1g, const float* __restrict__ rsum,
    const unsigned short* __restrict__ apad, const unsigned short* __restrict__ w2t,
    const float* __restrict__ b1,
    const float* __restrict__ bn1_g, const float* __restrict__ bn1_b,
    const float* __restrict__ bn1_m, const float* __restrict__ bn1_v,
    const float* __restrict__ b2,
    const float* __restrict__ bn2_g, const float* __restrict__ bn2_b,
    const float* __restrict__ bn2_m, const float* __restrict__ bn2_v,
    const float4* __restrict__ d1r, float* __restrict__ part) {
  __shared__ unsigned short a_lds[NN * ALD];
  __shared__ unsigned short s2_lds[K2 * SLD];
  __shared__ unsigned short w2_lds[K2 * WLD];
  __shared__ float4 gp[K1];
  __shared__ float r_lds[NN];
  __shared__ float p2[3 * K2];
  __shared__ float red[12];

  int blk = blockIdx.x;
  int b = blk & 31, t = blk >> 5;
  int tid = threadIdx.x;
  int lane = tid & 63, wave = tid >> 6;
  int l15 = lane & 15, l4 = lane >> 4;

  {
    const uint4* src = (const uint4*)(apad + (size_t)b * NN * ALD);
    uint4* dst = (uint4*)a_lds;
    for (int i = tid; i < NN * ALD / 8; i += 256) dst[i] = src[i];
  }
  {
    const uint2* src = (const uint2*)w2t;
    uint2* dst = (uint2*)w2_lds;
    for (int i = tid; i < K2 * WLD / 4; i += 256) dst[i] = src[i];
  }
  if (tid < K1) {
    float s1v = s1g[((size_t)b * TT + t) * K1 + tid];
    float s = bn1_g[tid] * rsqrtf(bn1_v[tid] + EPSV);
    gp[tid] = make_float4(s1v, b1[tid], s, bn1_b[tid] - bn1_m[tid] * s);
  }
  if (tid >= 64 && tid < 64 + NN) r_lds[tid - 64] = rsum[b * NN + (tid - 64)];
  if (tid >= 192 && tid < 192 + K2) {
    int m = tid - 192;
    float s = bn2_g[m] * rsqrtf(bn2_v[m] + EPSV);
    p2[m] = b2[m];
    p2[K2 + m] = s;
    p2[2 * K2 + m] = bn2_b[m] - bn2_m[m] * s;
  }
  __syncthreads();

  f32x4 z4 = {0.f, 0.f, 0.f, 0.f};

  {
    float rj0 = r_lds[(wave * 2 + 0) * 16 + l15];
    float rj1 = r_lds[(wave * 2 + 1) * 16 + l15];
    f32x4 acc[2][2];
    acc[0][0] = z4; acc[0][1] = z4; acc[1][0] = z4; acc[1][1] = z4;
#pragma unroll
    for (int kt = 0; kt < 2; ++kt) {
      float4 gpv[8];
#pragma unroll
      for (int e = 0; e < 8; ++e) gpv[e] = gp[kt * 32 + l4 * 8 + e];
      short8 bfrag0 = *((const short8*)&w2_lds[(0 + l15) * WLD + kt * 32 + l4 * 8]);
      short8 bfrag1 = *((const short8*)&w2_lds[(16 + l15) * WLD + kt * 32 + l4 * 8]);
#pragma unroll
      for (int jt = 0; jt < 2; ++jt) {
        float rj = jt ? rj1 : rj0;
        short8 af;
#pragma unroll
        for (int e = 0; e < 8; ++e) {
          float4 p = gpv[e];
          float v = leaky_(rj * p.x + p.y) * p.z + p.w;
          af[e] = (short)f2bf(v);
        }
        acc[jt][0] = __builtin_amdgcn_mfma_f32_16x16x32_bf16(af, bfrag0, acc[jt][0], 0, 0, 0);
        acc[jt][1] = __builtin_amdgcn_mfma_f32_16x16x32_bf16(af, bfrag1, acc[jt][1], 0, 0, 0);
      }
    }
#pragma unroll
    for (int jt = 0; jt < 2; ++jt) {
      int jbase = (wave * 2 + jt) * 16 + l4 * 4;
#pragma unroll
      for (int mt = 0; mt < 2; ++mt) {
        int m = mt * 16 + l15;
        unsigned lo = (unsigned)f2bf(acc[jt][mt][0]) | ((unsigned)f2bf(acc[jt][mt][1]) << 16);
        unsigned hi = (unsigned)f2bf(acc[jt][mt][2]) | ((unsigned)f2bf(acc[jt][mt][3]) << 16);
        uint2 val; val.x = lo; val.y = hi;
        *((uint2*)&s2_lds[m * SLD + jbase]) = val;
      }
    }
  }
  __syncthreads();

  float c0 = 0.f, c1 = 0.f, c2 = 0.f;
  {
    f32x4 acc[2][2];
    acc[0][0] = z4; acc[0][1] = z4; acc[1][0] = z4; acc[1][1] = z4;
#pragma unroll
    for (int kt = 0; kt < 4; ++kt) {
      short8 bfrag0 = *((const short8*)&s2_lds[(0 + l15) * SLD + kt * 32 + l4 * 8]);
      short8 bfrag1 = *((const short8*)&s2_lds[(16 + l15) * SLD + kt * 32 + l4 * 8]);
#pragma unroll
      for (int it = 0; it < 2; ++it) {
        int i = (wave * 2 + it) * 16 + l15;
        short8 afrag = *((const short8*)&a_lds[i * ALD + kt * 32 + l4 * 8]);
        acc[it][0] = __builtin_amdgcn_mfma_f32_16x16x32_bf16(afrag, bfrag0, acc[it][0], 0, 0, 0);
        acc[it][1] = __builtin_amdgcn_mfma_f32_16x16x32_bf16(afrag, bfrag1, acc[it][1], 0, 0, 0);
      }
    }
    float gv[2][2][4];
#pragma unroll
    for (int it = 0; it < 2; ++it)
#pragma unroll
      for (int mt = 0; mt < 2; ++mt) {
        int m = mt * 16 + l15;
        float bb = p2[m], bs = p2[K2 + m], bo = p2[2 * K2 + m];
#pragma unroll
        for (int r = 0; r < 4; ++r) gv[it][mt][r] = leaky_(acc[it][mt][r] + bb) * bs + bo;
      }
#pragma unroll
    for (int g = 0; g < 4; ++g) {
      int it = g >> 1, mt = g & 1;
      float4 v0 = d1r[(((size_t)t * 4 + g) * 3 + 0) * 256 + tid];
      float4 v1 = d1r[(((size_t)t * 4 + g) * 3 + 1) * 256 + tid];
      float4 v2 = d1r[(((size_t)t * 4 + g) * 3 + 2) * 256 + tid];
      c0 += gv[it][mt][0] * v0.x + gv[it][mt][1] * v0.y + gv[it][mt][2] * v0.z + gv[it][mt][3] * v0.w;
      c1 += gv[it][mt][0] * v1.x + gv[it][mt][1] * v1.y + gv[it][mt][2] * v1.z + gv[it][mt][3] * v1.w;
      c2 += gv[it][mt][0] * v2.x + gv[it][mt][1] * v2.y + gv[it][mt][2] * v2.z + gv[it][mt][3] * v2.w;
    }
  }
#pragma unroll
  for (int off = 32; off >= 1; off >>= 1) {
    c0 += __shfl_down(c0, off);
    c1 += __shfl_down(c1, off);
    c2 += __shfl_down(c2, off);
  }
  if (lane == 0) { red[wave * 3 + 0] = c0; red[wave * 3 + 1] = c1; red[wave * 3 + 2] = c2; }
  __syncthreads();
  if (tid == 0) {
    float s0 = 0.f, s1v = 0.f, s2v = 0.f;
    for (int w = 0; w < 4; ++w) { s0 += red[w * 3]; s1v += red[w * 3 + 1]; s2v += red[w * 3 + 2]; }
    part[((size_t)b * TT + t) * 3 + 0] = s0;
    part[((size_t)b * TT + t) * 3 + 1] = s1v;
    part[((size_t)b * TT + t) * 3 + 2] = s2v;
  }
}

// ---------------- final: reduce partials over t, relu, d2 ----------------
__global__ __launch_bounds__(128) void k_out(const float* __restrict__ part,
                                             const float* __restrict__ d1b,
                                             const float* __restrict__ d2w,
                                             const float* __restrict__ d2b,
                                             float* __restrict__ out) {
  int b = blockIdx.x, n = threadIdx.x;
  float s[3] = {0.f, 0.f, 0.f};
  const float* p = part + (size_t)b * TT * 3;
  for (int t = 0; t < TT; ++t) {
    s[0] += p[t * 3];
    s[1] += p[t * 3 + 1];
    s[2] += p[t * 3 + 2];
  }
  float o = d2b[n];
#pragma unroll
  for (int c = 0; c < 3; ++c) {
    float d = s[c] + d1b[c];
    d = d > 0.f ? d : 0.f;
    o += d * d2w[c * NN + n];
  }
  out[b * NN + n] = o;
}

extern "C" void kernel_launch(void* const* d_in, const int* in_sizes, int n_in,
                              void* d_out, int out_size, void* d_ws, size_t ws_size,
                              hipStream_t stream) {
  const float* x      = (const float*)d_in[0];
  const float* a      = (const float*)d_in[1];
  const float* lstm_k = (const float*)d_in[2];
  const float* lstm_r = (const float*)d_in[3];
  const float* lstm_b = (const float*)d_in[4];
  const float* bnl_g  = (const float*)d_in[5];
  const float* bnl_b  = (const float*)d_in[6];
  const float* bnl_m  = (const float*)d_in[7];
  const float* bnl_v  = (const float*)d_in[8];
  const float* w1     = (const float*)d_in[9];
  const float* b1     = (const float*)d_in[10];
  const float* bn1_g  = (const float*)d_in[11];
  const float* bn1_b  = (const float*)d_in[12];
  const float* bn1_m  = (const float*)d_in[13];
  const float* bn1_v  = (const float*)d_in[14];
  const float* w2     = (const float*)d_in[15];
  const float* b2     = (const float*)d_in[16];
  const float* bn2_g  = (const float*)d_in[17];
  const float* bn2_b  = (const float*)d_in[18];
  const float* bn2_m  = (const float*)d_in[19];
  const float* bn2_v  = (const float*)d_in[20];
  const float* d1_w   = (const float*)d_in[21];
  const float* d1_b   = (const float*)d_in[22];
  const float* d2_w   = (const float*)d_in[23];
  const float* d2_b   = (const float*)d_in[24];
  float* out = (float*)d_out;

  char* ws = (char*)d_ws;
  float* xz            = (float*)(ws + 0);                 // 2,097,152 B
  float* s1            = (float*)(ws + 2097152);           //   524,288 B
  float* rsum          = (float*)(ws + 2621440);           //    16,384 B
  float* part          = (float*)(ws + 2637824);           //    24,576 B
  unsigned short* apad = (unsigned short*)(ws + 2662400);  // 1,114,112 B
  unsigned short* w2t  = (unsigned short*)(ws + 3776512);  //     4,608 B
  unsigned* wrp        = (unsigned*)(ws + 3781120);        //    32,768 B
  unsigned* w1p        = (unsigned*)(ws + 3813888);        //     8,192 B
  float4* d1r          = (float4*)(ws + 3822080);          // 3,145,728 B

  k_xzp<<<258, 256, 0, stream>>>(x, lstm_k, lstm_b, lstm_r, w1, xz, wrp, w1p);
  k_mega<<<129, 256, 0, stream>>>(xz, wrp, w1p, bnl_g, bnl_b, bnl_m, bnl_v,
                                  a, w2, d1_w, s1, rsum, apad, w2t, d1r);
  k_gcn<<<BB * TT, 256, 0, stream>>>(s1, rsum, apad, w2t, b1, bn1_g, bn1_b, bn1_m, bn1_v,
                                     b2, bn2_g, bn2_b, bn2_m, bn2_v, d1r, part);
  k_out<<<BB, 128, 0, stream>>>(part, d1_b, d2_w, d2_b, out);
}

// Round 14
// 71.487 us; speedup vs baseline: 1.6414x; 1.0114x over previous
//
#include <hip/hip_runtime.h>

#define BB 32
#define TT 64
#define NN 128
#define FF 128
#define UU 64
#define K1 64
#define K2 32
#define G4 256
#define EPSV 1e-3f
#define SLOPE 0.01f

#define ALD 136
#define SLD 136
#define WLD 72

typedef __attribute__((ext_vector_type(8))) short short8;
typedef __attribute__((ext_vector_type(4))) float f32x4;
typedef __attribute__((ext_vector_type(2))) __fp16 half2v;

__device__ __forceinline__ float sigmoidf_(float x) {
  return __builtin_amdgcn_rcpf(1.f + __expf(-x));
}
__device__ __forceinline__ float tanhf_(float x) {
  return 1.f - 2.f * __builtin_amdgcn_rcpf(__expf(2.f * x) + 1.f);
}
__device__ __forceinline__ float leaky_(float x) { return x >= 0.f ? x : SLOPE * x; }
__device__ __forceinline__ unsigned short f2bf(float x) {
  union { float f; unsigned u; } v; v.f = x;
  unsigned r = v.u + 0x7fff + ((v.u >> 16) & 1);
  return (unsigned short)(r >> 16);
}

// ---------------- K1: xz GEMM (blocks 0..255) + weight packing (256,257) ----------------
__global__ __launch_bounds__(256) void k_xzp(const float* __restrict__ x,
                                             const float* __restrict__ wk,
                                             const float* __restrict__ bias,
                                             const float* __restrict__ wr,
                                             const float* __restrict__ w1,
                                             float* __restrict__ xz,
                                             unsigned* __restrict__ wrp,
                                             unsigned* __restrict__ w1p) {
  int tid = threadIdx.x;
  if (blockIdx.x < 256) {
    __shared__ float xs[8][FF];
    int row0 = blockIdx.x * 8;
    for (int i = tid; i < 8 * FF; i += 256) xs[i >> 7][i & 127] = x[(size_t)row0 * FF + i];
    __syncthreads();
    int g = tid;
    float acc[8];
    float bg = bias[g];
#pragma unroll
    for (int r = 0; r < 8; ++r) acc[r] = bg;
    for (int f = 0; f < FF; ++f) {
      float w = wk[f * G4 + g];
#pragma unroll
      for (int r = 0; r < 8; ++r) acc[r] += xs[r][f] * w;
    }
#pragma unroll
    for (int r = 0; r < 8; ++r) xz[(size_t)(row0 + r) * G4 + g] = acc[r];
  } else if (blockIdx.x == 256) {
    // pack Wr f16x2, lane-contiguous: wrp[u*128 + gate*32 + p]
    for (int idx = tid; idx < 4 * 32 * UU; idx += 256) {
      int p = idx & 31;
      int gate = (idx >> 5) & 3;
      int u = idx >> 7;
      int col = gate * UU + u;
      union { __fp16 h[2]; unsigned u; } pk;
      pk.h[0] = (__fp16)wr[(2 * p) * G4 + col];
      pk.h[1] = (__fp16)wr[(2 * p + 1) * G4 + col];
      wrp[idx] = pk.u;
    }
  } else {
    // pack w1 f16x2, lane-contiguous: w1p[k*32 + p]
    for (int idx = tid; idx < 32 * K1; idx += 256) {
      int p = idx & 31, k = idx >> 5;
      union { __fp16 h[2]; unsigned u; } pk;
      pk.h[0] = (__fp16)w1[(2 * p) * K1 + k];
      pk.h[1] = (__fp16)w1[(2 * p + 1) * K1 + k];
      w1p[idx] = pk.u;
    }
  }
}

// ---------------- K2 mega: scan (0..31) + prep on idle CUs (32..128) ----------------
// h16 RAW (write as fp16, read as uint4, no barrier between) is pinned with
// sched_barrier(0): same-wave LDS pipe is in-order, so program order suffices.
__global__ __launch_bounds__(256, 1) void k_mega(
    const float* __restrict__ xz, const unsigned* __restrict__ wrp,
    const unsigned* __restrict__ w1p,
    const float* __restrict__ bnl_g, const float* __restrict__ bnl_b,
    const float* __restrict__ bnl_m, const float* __restrict__ bnl_v,
    const float* __restrict__ a, const float* __restrict__ w2,
    const float* __restrict__ d1w,
    float* __restrict__ s1out, float* __restrict__ rsum,
    unsigned short* __restrict__ apad, unsigned short* __restrict__ w2t,
    float4* __restrict__ d1r) {
  __shared__ __align__(16) char smem[76032];
  int tid = threadIdx.x;
  int blk = blockIdx.x;

  if (blk < 32) {
    float* xz_lds = (float*)smem;                    // 64 KB
    __fp16* hp = (__fp16*)(smem + 65536);            // 8 KB
    float* zex = (float*)(smem + 73728);             // 2 KB
    __fp16* h16 = (__fp16*)(smem + 75776);           // 256 B
    int wave = tid >> 6, lane = tid & 63;
    int role = wave & 1;
    int b = blk;

    {  // cooperative xz stage
      const float4* src = (const float4*)(xz + (size_t)b * TT * G4);
      float4* dst = (float4*)xz_lds;
#pragma unroll
      for (int k = 0; k < 16; ++k) dst[tid + k * 256] = src[tid + k * 256];
    }
    unsigned wv0[32], wv1[32];
    if (wave < 2) {
      const uint4* wp = (const uint4*)(wrp + (size_t)lane * 128 + role * 64);
#pragma unroll
      for (int k = 0; k < 8; ++k) {
        uint4 v = wp[k];
        wv0[4 * k + 0] = v.x; wv0[4 * k + 1] = v.y; wv0[4 * k + 2] = v.z; wv0[4 * k + 3] = v.w;
      }
#pragma unroll
      for (int k = 0; k < 8; ++k) {
        uint4 v = wp[8 + k];
        wv1[4 * k + 0] = v.x; wv1[4 * k + 1] = v.y; wv1[4 * k + 2] = v.z; wv1[4 * k + 3] = v.w;
      }
      h16[wave * UU + lane] = (__fp16)0.f;
    }
    float bscale = bnl_g[lane] * rsqrtf(bnl_v[lane] + EPSV);
    float boff = bnl_b[lane] - bnl_m[lane] * bscale;
    float c = 0.f;
    __syncthreads();

    for (int t = 0; t < TT; ++t) {
      int par = t & 1;
      float z0, z1;
      if (wave < 2) {
        __builtin_amdgcn_sched_barrier(0);  // h16 reads must not move above prior write
        unsigned hw[32];
        const uint4* hq = (const uint4*)(h16 + wave * UU);
#pragma unroll
        for (int k = 0; k < 8; ++k) {
          uint4 v = hq[k];
          hw[4 * k + 0] = v.x; hw[4 * k + 1] = v.y; hw[4 * k + 2] = v.z; hw[4 * k + 3] = v.w;
        }
        z0 = xz_lds[t * G4 + role * 128 + lane];
        z1 = xz_lds[t * G4 + role * 128 + 64 + lane];
#pragma unroll
        for (int p = 0; p < 32; ++p) {
          half2v hh = __builtin_bit_cast(half2v, hw[p]);
          z0 = __builtin_amdgcn_fdot2(__builtin_bit_cast(half2v, wv0[p]), hh, z0, false);
          z1 = __builtin_amdgcn_fdot2(__builtin_bit_cast(half2v, wv1[p]), hh, z1, false);
        }
        zex[(par * 2 + role) * 128 + lane] = z0;
        zex[(par * 2 + role) * 128 + 64 + lane] = z1;
      }
      __syncthreads();
      if (wave < 2) {
        float pz0 = zex[(par * 2 + (role ^ 1)) * 128 + lane];
        float pz1 = zex[(par * 2 + (role ^ 1)) * 128 + 64 + lane];
        float zi = role ? pz0 : z0;
        float zf = role ? pz1 : z1;
        float zg = role ? z0 : pz0;
        float zo = role ? z1 : pz1;
        float i_ = sigmoidf_(zi), f_ = sigmoidf_(zf), g_ = tanhf_(zg), o_ = sigmoidf_(zo);
        c = f_ * c + i_ * g_;
        float h = o_ * tanhf_(c);
        h16[wave * UU + lane] = (__fp16)h;
        __builtin_amdgcn_sched_barrier(0);  // pin write before next iter's reads
        if (role == 0) hp[t * UU + lane] = (__fp16)(h * bscale + boff);
      }
    }
    __syncthreads();

    unsigned w1v[32];
    {
      const uint4* wp1 = (const uint4*)(w1p + (size_t)lane * 32);
#pragma unroll
      for (int k = 0; k < 8; ++k) {
        uint4 v = wp1[k];
        w1v[4 * k + 0] = v.x; w1v[4 * k + 1] = v.y; w1v[4 * k + 2] = v.z; w1v[4 * k + 3] = v.w;
      }
    }
    float* s1b = s1out + (size_t)b * TT * K1;
    for (int r = 0; r < 16; ++r) {
      int t = wave * 16 + r;
      unsigned hw2[32];
      const uint4* hq = (const uint4*)(hp + t * UU);
#pragma unroll
      for (int k = 0; k < 8; ++k) {
        uint4 v = hq[k];
        hw2[4 * k + 0] = v.x; hw2[4 * k + 1] = v.y; hw2[4 * k + 2] = v.z; hw2[4 * k + 3] = v.w;
      }
      float acc = 0.f;
#pragma unroll
      for (int p = 0; p < 32; ++p)
        acc = __builtin_amdgcn_fdot2(__builtin_bit_cast(half2v, w1v[p]),
                                     __builtin_bit_cast(half2v, hw2[p]), acc, false);
      s1b[t * K1 + lane] = acc;
    }
  } else if (blk < 64) {
    int b = blk - 32;
    int wave = tid >> 6, lane = tid & 63;
    const float* ab = a + (size_t)b * NN * NN;
    for (int r = 0; r < 32; ++r) {
      int row = wave * 32 + r;
      float2 v = *(const float2*)(ab + (size_t)row * NN + lane * 2);
      float s = v.x + v.y;
#pragma unroll
      for (int off = 32; off >= 1; off >>= 1) s += __shfl_down(s, off);
      if (lane == 0) rsum[b * NN + row] = s;
    }
    unsigned short* ap = apad + (size_t)b * NN * ALD;
    for (int idx = tid; idx < NN * NN; idx += 256) {
      int i = idx >> 7, j = idx & 127;
      ap[i * ALD + j] = f2bf(ab[idx]);
    }
  } else if (blk == 64) {
    for (int idx = tid; idx < K1 * K2; idx += 256) {
      int k = idx >> 5, m = idx & 31;
      w2t[m * WLD + k] = f2bf(w2[idx]);
    }
  } else {
    int t = blk - 65;
    float* dt = (float*)smem;  // 12 KB
    const float* src = d1w + (size_t)t * NN * K2 * 3;
    for (int c32 = 0; c32 < 4; ++c32) {
      __syncthreads();
      for (int i = tid; i < 768; i += 256)
        ((float4*)dt)[i] = ((const float4*)(src + c32 * 3072))[i];
      __syncthreads();
#pragma unroll
      for (int q = 0; q < 3; ++q) {
        int item = q * 256 + tid;
        int l = item & 63;
        int gc = item >> 6;
        int g = gc / 3, cc = gc % 3;
        int it = g >> 1, mt = g & 1;
        int l15v = l & 15, l4v = l >> 4;
        int m = mt * 16 + l15v;
        int rowbase = it * 16 + l4v * 4;
        float4 v;
        v.x = dt[(rowbase + 0) * 96 + m * 3 + cc];
        v.y = dt[(rowbase + 1) * 96 + m * 3 + cc];
        v.z = dt[(rowbase + 2) * 96 + m * 3 + cc];
        v.w = dt[(rowbase + 3) * 96 + m * 3 + cc];
        d1r[(((size_t)t * 4 + g) * 3 + cc) * 256 + c32 * 64 + l] = v;
      }
    }
  }
}

// ---------------- fused GCN1+GCN2+d1 partial: 2 timesteps per block ----------------
// a_lds/w2_lds staged ONCE per 2 t's (staging is the dominant serial term);
// round-8 proven barrier pattern inside the t-loop; d1 partials accumulated
// across both t's -> part[(b, tg)] with 32 groups.
__global__ __launch_bounds__(256) void k_gcn(
    const float* __restrict__ s1g, const float* __restrict__ rsum,
    const unsigned short* __restrict__ apad, const unsigned short* __restrict__ w2t,
    const float* __restrict__ b1,
    const float* __restrict__ bn1_g, const float* __restrict__ bn1_b,
    const float* __restrict__ bn1_m, const float* __restrict__ bn1_v,
    const float* __restrict__ b2,
    const float* __restrict__ bn2_g, const float* __restrict__ bn2_b,
    const float* __restrict__ bn2_m, const float* __restrict__ bn2_v,
    const float4* __restrict__ d1r, float* __restrict__ part) {
  __shared__ unsigned short a_lds[NN * ALD];   // 34816 B
  __shared__ unsigned short s2_lds[K2 * SLD];  // 8704 B
  __shared__ unsigned short w2_lds[K2 * WLD];  // 4608 B
  __shared__ float s1l[2][K1];                 // 512 B
  __shared__ float4 gp[K1];                    // (b1, bn1_scale, bn1_off, -)
  __shared__ float r_lds[NN];
  __shared__ float p2[3 * K2];
  __shared__ float red[12];

  int blk = blockIdx.x;
  int b = blk & 31, tg = blk >> 5;   // tg-major: consecutive blocks share d1r t-slices
  int t0 = tg * 2;
  int tid = threadIdx.x;
  int lane = tid & 63, wave = tid >> 6;
  int l15 = lane & 15, l4 = lane >> 4;

  {
    const uint4* src = (const uint4*)(apad + (size_t)b * NN * ALD);
    uint4* dst = (uint4*)a_lds;
    for (int i = tid; i < NN * ALD / 8; i += 256) dst[i] = src[i];
  }
  {
    const uint2* src = (const uint2*)w2t;
    uint2* dst = (uint2*)w2_lds;
    for (int i = tid; i < K2 * WLD / 4; i += 256) dst[i] = src[i];
  }
  if (tid < 128) ((float*)s1l)[tid] = s1g[((size_t)b * TT + t0) * K1 + tid];
  if (tid < K1) {
    float s = bn1_g[tid] * rsqrtf(bn1_v[tid] + EPSV);
    gp[tid] = make_float4(b1[tid], s, bn1_b[tid] - bn1_m[tid] * s, 0.f);
  }
  if (tid >= 64 && tid < 192) r_lds[tid - 64] = rsum[b * NN + (tid - 64)];
  if (tid >= 192 && tid < 192 + K2) {
    int m = tid - 192;
    float s = bn2_g[m] * rsqrtf(bn2_v[m] + EPSV);
    p2[m] = b2[m];
    p2[K2 + m] = s;
    p2[2 * K2 + m] = bn2_b[m] - bn2_m[m] * s;
  }
  __syncthreads();

  f32x4 z4 = {0.f, 0.f, 0.f, 0.f};
  float rj0 = r_lds[(wave * 2 + 0) * 16 + l15];
  float rj1 = r_lds[(wave * 2 + 1) * 16 + l15];
  // hoist w2 B-fragments (t-invariant)
  short8 bw[2][2];
#pragma unroll
  for (int kt = 0; kt < 2; ++kt) {
    bw[kt][0] = *((const short8*)&w2_lds[(0 + l15) * WLD + kt * 32 + l4 * 8]);
    bw[kt][1] = *((const short8*)&w2_lds[(16 + l15) * WLD + kt * 32 + l4 * 8]);
  }

  float c0 = 0.f, c1 = 0.f, c2 = 0.f;

  for (int ti = 0; ti < 2; ++ti) {
    int t = t0 + ti;
    // ---- phase 1: g1 frags in-register, MFMA -> sup2 ----
    f32x4 a1[2][2];
    a1[0][0] = z4; a1[0][1] = z4; a1[1][0] = z4; a1[1][1] = z4;
#pragma unroll
    for (int kt = 0; kt < 2; ++kt) {
      float4 gpv[8];
      float s1v[8];
#pragma unroll
      for (int e = 0; e < 8; ++e) {
        gpv[e] = gp[kt * 32 + l4 * 8 + e];
        s1v[e] = s1l[ti][kt * 32 + l4 * 8 + e];
      }
#pragma unroll
      for (int jt = 0; jt < 2; ++jt) {
        float rj = jt ? rj1 : rj0;
        short8 af;
#pragma unroll
        for (int e = 0; e < 8; ++e) {
          float4 p = gpv[e];
          float v = leaky_(rj * s1v[e] + p.x) * p.y + p.z;
          af[e] = (short)f2bf(v);
        }
        a1[jt][0] = __builtin_amdgcn_mfma_f32_16x16x32_bf16(af, bw[kt][0], a1[jt][0], 0, 0, 0);
        a1[jt][1] = __builtin_amdgcn_mfma_f32_16x16x32_bf16(af, bw[kt][1], a1[jt][1], 0, 0, 0);
      }
    }
    __syncthreads();   // (a) previous t's phase-2 s2_lds reads complete
#pragma unroll
    for (int jt = 0; jt < 2; ++jt) {
      int jbase = (wave * 2 + jt) * 16 + l4 * 4;
#pragma unroll
      for (int mt = 0; mt < 2; ++mt) {
        int m = mt * 16 + l15;
        unsigned lo = (unsigned)f2bf(a1[jt][mt][0]) | ((unsigned)f2bf(a1[jt][mt][1]) << 16);
        unsigned hi = (unsigned)f2bf(a1[jt][mt][2]) | ((unsigned)f2bf(a1[jt][mt][3]) << 16);
        uint2 val; val.x = lo; val.y = hi;
        *((uint2*)&s2_lds[m * SLD + jbase]) = val;
      }
    }
    __syncthreads();   // (b) s2 visible

    // ---- phase 2: g2 = a @ sup2 (MFMA), fused leaky+BN2+d1 dot ----
    f32x4 acc[2][2];
    acc[0][0] = z4; acc[0][1] = z4; acc[1][0] = z4; acc[1][1] = z4;
#pragma unroll
    for (int kt = 0; kt < 4; ++kt) {
      short8 bfrag0 = *((const short8*)&s2_lds[(0 + l15) * SLD + kt * 32 + l4 * 8]);
      short8 bfrag1 = *((const short8*)&s2_lds[(16 + l15) * SLD + kt * 32 + l4 * 8]);
#pragma unroll
      for (int it = 0; it < 2; ++it) {
        int i = (wave * 2 + it) * 16 + l15;
        short8 afrag = *((const short8*)&a_lds[i * ALD + kt * 32 + l4 * 8]);
        acc[it][0] = __builtin_amdgcn_mfma_f32_16x16x32_bf16(afrag, bfrag0, acc[it][0], 0, 0, 0);
        acc[it][1] = __builtin_amdgcn_mfma_f32_16x16x32_bf16(afrag, bfrag1, acc[it][1], 0, 0, 0);
      }
    }
    float gv[2][2][4];
#pragma unroll
    for (int it = 0; it < 2; ++it)
#pragma unroll
      for (int mt = 0; mt < 2; ++mt) {
        int m = mt * 16 + l15;
        float bb = p2[m], bs = p2[K2 + m], bo = p2[2 * K2 + m];
#pragma unroll
        for (int r = 0; r < 4; ++r) gv[it][mt][r] = leaky_(acc[it][mt][r] + bb) * bs + bo;
      }
#pragma unroll
    for (int g = 0; g < 4; ++g) {
      int it = g >> 1, mt = g & 1;
      float4 v0 = d1r[(((size_t)t * 4 + g) * 3 + 0) * 256 + tid];
      float4 v1 = d1r[(((size_t)t * 4 + g) * 3 + 1) * 256 + tid];
      float4 v2 = d1r[(((size_t)t * 4 + g) * 3 + 2) * 256 + tid];
      c0 += gv[it][mt][0] * v0.x + gv[it][mt][1] * v0.y + gv[it][mt][2] * v0.z + gv[it][mt][3] * v0.w;
      c1 += gv[it][mt][0] * v1.x + gv[it][mt][1] * v1.y + gv[it][mt][2] * v1.z + gv[it][mt][3] * v1.w;
      c2 += gv[it][mt][0] * v2.x + gv[it][mt][1] * v2.y + gv[it][mt][2] * v2.z + gv[it][mt][3] * v2.w;
    }
  }

#pragma unroll
  for (int off = 32; off >= 1; off >>= 1) {
    c0 += __shfl_down(c0, off);
    c1 += __shfl_down(c1, off);
    c2 += __shfl_down(c2, off);
  }
  if (lane == 0) { red[wave * 3 + 0] = c0; red[wave * 3 + 1] = c1; red[wave * 3 + 2] = c2; }
  __syncthreads();
  if (tid == 0) {
    float s0 = 0.f, s1v = 0.f, s2v = 0.f;
    for (int w = 0; w < 4; ++w) { s0 += red[w * 3]; s1v += red[w * 3 + 1]; s2v += red[w * 3 + 2]; }
    part[((size_t)b * 32 + tg) * 3 + 0] = s0;
    part[((size_t)b * 32 + tg) * 3 + 1] = s1v;
    part[((size_t)b * 32 + tg) * 3 + 2] = s2v;
  }
}

// ---------------- final: reduce 32 partials, relu, d2 ----------------
__global__ __launch_bounds__(128) void k_out(const float* __restrict__ part,
                                             const float* __restrict__ d1b,
                                             const float* __restrict__ d2w,
                                             const float* __restrict__ d2b,
                                             float* __restrict__ out) {
  int b = blockIdx.x, n = threadIdx.x;
  float s[3] = {0.f, 0.f, 0.f};
  const float* p = part + (size_t)b * 32 * 3;
#pragma unroll
  for (int g = 0; g < 32; ++g) {
    s[0] += p[g * 3];
    s[1] += p[g * 3 + 1];
    s[2] += p[g * 3 + 2];
  }
  float o = d2b[n];
#pragma unroll
  for (int c = 0; c < 3; ++c) {
    float d = s[c] + d1b[c];
    d = d > 0.f ? d : 0.f;
    o += d * d2w[c * NN + n];
  }
  out[b * NN + n] = o;
}

extern "C" void kernel_launch(void* const* d_in, const int* in_sizes, int n_in,
                              void* d_out, int out_size, void* d_ws, size_t ws_size,
                              hipStream_t stream) {
  const float* x      = (const float*)d_in[0];
  const float* a      = (const float*)d_in[1];
  const float* lstm_k = (const float*)d_in[2];
  const float* lstm_r = (const float*)d_in[3];
  const float* lstm_b = (const float*)d_in[4];
  const float* bnl_g  = (const float*)d_in[5];
  const float* bnl_b  = (const float*)d_in[6];
  const float* bnl_m  = (const float*)d_in[7];
  const float* bnl_v  = (const float*)d_in[8];
  const float* w1     = (const float*)d_in[9];
  const float* b1     = (const float*)d_in[10];
  const float* bn1_g  = (const float*)d_in[11];
  const float* bn1_b  = (const float*)d_in[12];
  const float* bn1_m  = (const float*)d_in[13];
  const float* bn1_v  = (const float*)d_in[14];
  const float* w2     = (const float*)d_in[15];
  const float* b2     = (const float*)d_in[16];
  const float* bn2_g  = (const float*)d_in[17];
  const float* bn2_b  = (const float*)d_in[18];
  const float* bn2_m  = (const float*)d_in[19];
  const float* bn2_v  = (const float*)d_in[20];
  const float* d1_w   = (const float*)d_in[21];
  const float* d1_b   = (const float*)d_in[22];
  const float* d2_w   = (const float*)d_in[23];
  const float* d2_b   = (const float*)d_in[24];
  float* out = (float*)d_out;

  char* ws = (char*)d_ws;
  float* xz            = (float*)(ws + 0);                 // 2,097,152 B
  float* s1            = (float*)(ws + 2097152);           //   524,288 B
  float* rsum          = (float*)(ws + 2621440);           //    16,384 B
  float* part          = (float*)(ws + 2637824);           //    24,576 B
  unsigned short* apad = (unsigned short*)(ws + 2662400);  // 1,114,112 B
  unsigned short* w2t  = (unsigned short*)(ws + 3776512);  //     4,608 B
  unsigned* wrp        = (unsigned*)(ws + 3781120);        //    32,768 B
  unsigned* w1p        = (unsigned*)(ws + 3813888);        //     8,192 B
  float4* d1r          = (float4*)(ws + 3822080);          // 3,145,728 B

  k_xzp<<<258, 256, 0, stream>>>(x, lstm_k, lstm_b, lstm_r, w1, xz, wrp, w1p);
  k_mega<<<129, 256, 0, stream>>>(xz, wrp, w1p, bnl_g, bnl_b, bnl_m, bnl_v,
                                  a, w2, d1_w, s1, rsum, apad, w2t, d1r);
  k_gcn<<<1024, 256, 0, stream>>>(s1, rsum, apad, w2t, b1, bn1_g, bn1_b, bn1_m, bn1_v,
                                  b2, bn2_g, bn2_b, bn2_m, bn2_v, d1r, part);
  k_out<<<BB, 128, 0, stream>>>(part, d1_b, d2_w, d2_b, out);
}

// Round 16
// 69.851 us; speedup vs baseline: 1.6798x; 1.0234x over previous
//
#include <hip/hip_runtime.h>

#define BB 32
#define TT 64
#define NN 128
#define FF 128
#define UU 64
#define K1 64
#define K2 32
#define G4 256
#define EPSV 1e-3f
#define SLOPE 0.01f

#define ALD 136
#define SLD 136
#define WLD 72

typedef __attribute__((ext_vector_type(8))) short short8;
typedef __attribute__((ext_vector_type(4))) float f32x4;
typedef __attribute__((ext_vector_type(2))) __fp16 half2v;

__device__ __forceinline__ float sigmoidf_(float x) {
  return __builtin_amdgcn_rcpf(1.f + __expf(-x));
}
__device__ __forceinline__ float tanhf_(float x) {
  return 1.f - 2.f * __builtin_amdgcn_rcpf(__expf(2.f * x) + 1.f);
}
__device__ __forceinline__ float leaky_(float x) { return x >= 0.f ? x : SLOPE * x; }
__device__ __forceinline__ unsigned short f2bf(float x) {
  union { float f; unsigned u; } v; v.f = x;
  unsigned r = v.u + 0x7fff + ((v.u >> 16) & 1);
  return (unsigned short)(r >> 16);
}

// ---------------- K1: xz GEMM (blocks 0..255) + weight packing (256,257) ----------------
__global__ __launch_bounds__(256) void k_xzp(const float* __restrict__ x,
                                             const float* __restrict__ wk,
                                             const float* __restrict__ bias,
                                             const float* __restrict__ wr,
                                             const float* __restrict__ w1,
                                             float* __restrict__ xz,
                                             unsigned* __restrict__ wrp,
                                             unsigned* __restrict__ w1p) {
  int tid = threadIdx.x;
  if (blockIdx.x < 256) {
    __shared__ float xs[8][FF];
    int row0 = blockIdx.x * 8;
    for (int i = tid; i < 8 * FF; i += 256) xs[i >> 7][i & 127] = x[(size_t)row0 * FF + i];
    __syncthreads();
    int g = tid;
    float acc[8];
    float bg = bias[g];
#pragma unroll
    for (int r = 0; r < 8; ++r) acc[r] = bg;
    for (int f = 0; f < FF; ++f) {
      float w = wk[f * G4 + g];
#pragma unroll
      for (int r = 0; r < 8; ++r) acc[r] += xs[r][f] * w;
    }
#pragma unroll
    for (int r = 0; r < 8; ++r) xz[(size_t)(row0 + r) * G4 + g] = acc[r];
  } else if (blockIdx.x == 256) {
    // pack Wr f16x2, lane-contiguous: wrp[u*128 + gate*32 + p]
    for (int idx = tid; idx < 4 * 32 * UU; idx += 256) {
      int p = idx & 31;
      int gate = (idx >> 5) & 3;
      int u = idx >> 7;
      int col = gate * UU + u;
      union { __fp16 h[2]; unsigned u; } pk;
      pk.h[0] = (__fp16)wr[(2 * p) * G4 + col];
      pk.h[1] = (__fp16)wr[(2 * p + 1) * G4 + col];
      wrp[idx] = pk.u;
    }
  } else {
    // pack w1 f16x2, lane-contiguous: w1p[k*32 + p]
    for (int idx = tid; idx < 32 * K1; idx += 256) {
      int p = idx & 31, k = idx >> 5;
      union { __fp16 h[2]; unsigned u; } pk;
      pk.h[0] = (__fp16)w1[(2 * p) * K1 + k];
      pk.h[1] = (__fp16)w1[(2 * p + 1) * K1 + k];
      w1p[idx] = pk.u;
    }
  }
}

// ---------------- K2 mega: scan (0..31) + prep on idle CUs (32..128) ----------------
// h16 RAW (fp16 write / uint4 read, same wave, no barrier) pinned with
// sched_barrier(0); in-order LDS pipe makes program order sufficient.
// fdot2 chain kept IN ORIGINAL ORDER (round-15 split-accumulator reverted:
// the reorder shifted the recurrent trajectory and blew the absmax margin).
__global__ __launch_bounds__(256, 1) void k_mega(
    const float* __restrict__ xz, const unsigned* __restrict__ wrp,
    const unsigned* __restrict__ w1p,
    const float* __restrict__ bnl_g, const float* __restrict__ bnl_b,
    const float* __restrict__ bnl_m, const float* __restrict__ bnl_v,
    const float* __restrict__ a, const float* __restrict__ w2,
    const float* __restrict__ d1w,
    float* __restrict__ s1out, float* __restrict__ rsum,
    unsigned short* __restrict__ apad, unsigned short* __restrict__ w2t,
    float4* __restrict__ d1r) {
  __shared__ __align__(16) char smem[76032];
  int tid = threadIdx.x;
  int blk = blockIdx.x;

  if (blk < 32) {
    float* xz_lds = (float*)smem;                    // 64 KB
    __fp16* hp = (__fp16*)(smem + 65536);            // 8 KB
    float* zex = (float*)(smem + 73728);             // 2 KB
    __fp16* h16 = (__fp16*)(smem + 75776);           // 256 B
    int wave = tid >> 6, lane = tid & 63;
    int role = wave & 1;
    int b = blk;

    {  // cooperative xz stage
      const float4* src = (const float4*)(xz + (size_t)b * TT * G4);
      float4* dst = (float4*)xz_lds;
#pragma unroll
      for (int k = 0; k < 16; ++k) dst[tid + k * 256] = src[tid + k * 256];
    }
    unsigned wv0[32], wv1[32];
    if (wave < 2) {
      const uint4* wp = (const uint4*)(wrp + (size_t)lane * 128 + role * 64);
#pragma unroll
      for (int k = 0; k < 8; ++k) {
        uint4 v = wp[k];
        wv0[4 * k + 0] = v.x; wv0[4 * k + 1] = v.y; wv0[4 * k + 2] = v.z; wv0[4 * k + 3] = v.w;
      }
#pragma unroll
      for (int k = 0; k < 8; ++k) {
        uint4 v = wp[8 + k];
        wv1[4 * k + 0] = v.x; wv1[4 * k + 1] = v.y; wv1[4 * k + 2] = v.z; wv1[4 * k + 3] = v.w;
      }
      h16[wave * UU + lane] = (__fp16)0.f;
    }
    float bscale = bnl_g[lane] * rsqrtf(bnl_v[lane] + EPSV);
    float boff = bnl_b[lane] - bnl_m[lane] * bscale;
    float c = 0.f;
    __syncthreads();

    for (int t = 0; t < TT; ++t) {
      int par = t & 1;
      float z0, z1;
      if (wave < 2) {
        __builtin_amdgcn_sched_barrier(0);  // h16 reads must not move above prior write
        unsigned hw[32];
        const uint4* hq = (const uint4*)(h16 + wave * UU);
#pragma unroll
        for (int k = 0; k < 8; ++k) {
          uint4 v = hq[k];
          hw[4 * k + 0] = v.x; hw[4 * k + 1] = v.y; hw[4 * k + 2] = v.z; hw[4 * k + 3] = v.w;
        }
        z0 = xz_lds[t * G4 + role * 128 + lane];
        z1 = xz_lds[t * G4 + role * 128 + 64 + lane];
#pragma unroll
        for (int p = 0; p < 32; ++p) {
          half2v hh = __builtin_bit_cast(half2v, hw[p]);
          z0 = __builtin_amdgcn_fdot2(__builtin_bit_cast(half2v, wv0[p]), hh, z0, false);
          z1 = __builtin_amdgcn_fdot2(__builtin_bit_cast(half2v, wv1[p]), hh, z1, false);
        }
        zex[(par * 2 + role) * 128 + lane] = z0;
        zex[(par * 2 + role) * 128 + 64 + lane] = z1;
      }
      __syncthreads();
      if (wave < 2) {
        float pz0 = zex[(par * 2 + (role ^ 1)) * 128 + lane];
        float pz1 = zex[(par * 2 + (role ^ 1)) * 128 + 64 + lane];
        float zi = role ? pz0 : z0;
        float zf = role ? pz1 : z1;
        float zg = role ? z0 : pz0;
        float zo = role ? z1 : pz1;
        float i_ = sigmoidf_(zi), f_ = sigmoidf_(zf), g_ = tanhf_(zg), o_ = sigmoidf_(zo);
        c = f_ * c + i_ * g_;
        float h = o_ * tanhf_(c);
        h16[wave * UU + lane] = (__fp16)h;
        __builtin_amdgcn_sched_barrier(0);  // pin write before next iter's reads
        if (role == 0) hp[t * UU + lane] = (__fp16)(h * bscale + boff);
      }
    }
    __syncthreads();

    unsigned w1v[32];
    {
      const uint4* wp1 = (const uint4*)(w1p + (size_t)lane * 32);
#pragma unroll
      for (int k = 0; k < 8; ++k) {
        uint4 v = wp1[k];
        w1v[4 * k + 0] = v.x; w1v[4 * k + 1] = v.y; w1v[4 * k + 2] = v.z; w1v[4 * k + 3] = v.w;
      }
    }
    float* s1b = s1out + (size_t)b * TT * K1;
    for (int r = 0; r < 16; ++r) {
      int t = wave * 16 + r;
      unsigned hw2[32];
      const uint4* hq = (const uint4*)(hp + t * UU);
#pragma unroll
      for (int k = 0; k < 8; ++k) {
        uint4 v = hq[k];
        hw2[4 * k + 0] = v.x; hw2[4 * k + 1] = v.y; hw2[4 * k + 2] = v.z; hw2[4 * k + 3] = v.w;
      }
      float acc = 0.f;
#pragma unroll
      for (int p = 0; p < 32; ++p)
        acc = __builtin_amdgcn_fdot2(__builtin_bit_cast(half2v, w1v[p]),
                                     __builtin_bit_cast(half2v, hw2[p]), acc, false);
      s1b[t * K1 + lane] = acc;
    }
  } else if (blk < 64) {
    int b = blk - 32;
    int wave = tid >> 6, lane = tid & 63;
    const float* ab = a + (size_t)b * NN * NN;
    for (int r = 0; r < 32; ++r) {
      int row = wave * 32 + r;
      float2 v = *(const float2*)(ab + (size_t)row * NN + lane * 2);
      float s = v.x + v.y;
#pragma unroll
      for (int off = 32; off >= 1; off >>= 1) s += __shfl_down(s, off);
      if (lane == 0) rsum[b * NN + row] = s;
    }
    unsigned short* ap = apad + (size_t)b * NN * ALD;
    for (int idx = tid; idx < NN * NN; idx += 256) {
      int i = idx >> 7, j = idx & 127;
      ap[i * ALD + j] = f2bf(ab[idx]);
    }
  } else if (blk == 64) {
    for (int idx = tid; idx < K1 * K2; idx += 256) {
      int k = idx >> 5, m = idx & 31;
      w2t[m * WLD + k] = f2bf(w2[idx]);
    }
  } else {
    int t = blk - 65;
    float* dt = (float*)smem;  // 12 KB
    const float* src = d1w + (size_t)t * NN * K2 * 3;
    for (int c32 = 0; c32 < 4; ++c32) {
      __syncthreads();
      for (int i = tid; i < 768; i += 256)
        ((float4*)dt)[i] = ((const float4*)(src + c32 * 3072))[i];
      __syncthreads();
#pragma unroll
      for (int q = 0; q < 3; ++q) {
        int item = q * 256 + tid;
        int l = item & 63;
        int gc = item >> 6;
        int g = gc / 3, cc = gc % 3;
        int it = g >> 1, mt = g & 1;
        int l15v = l & 15, l4v = l >> 4;
        int m = mt * 16 + l15v;
        int rowbase = it * 16 + l4v * 4;
        float4 v;
        v.x = dt[(rowbase + 0) * 96 + m * 3 + cc];
        v.y = dt[(rowbase + 1) * 96 + m * 3 + cc];
        v.z = dt[(rowbase + 2) * 96 + m * 3 + cc];
        v.w = dt[(rowbase + 3) * 96 + m * 3 + cc];
        d1r[(((size_t)t * 4 + g) * 3 + cc) * 256 + c32 * 64 + l] = v;
      }
    }
  }
}

// ---------------- fused GCN1+GCN2+d1: register A/B frags + 2 timesteps/block ----------------
// No a_lds/w2_lds: A-fragments (32 VGPR) and w2 B-fragments direct from L2-hot
// global. LDS ~11.5 KB -> high co-residency. 2 t's per block amortize frag/param
// loads; s2_lds reused with the proven double-barrier pattern.
__global__ __launch_bounds__(256) void k_gcn(
    const float* __restrict__ s1g, const float* __restrict__ rsum,
    const unsigned short* __restrict__ apad, const unsigned short* __restrict__ w2t,
    const float* __restrict__ b1,
    const float* __restrict__ bn1_g, const float* __restrict__ bn1_b,
    const float* __restrict__ bn1_m, const float* __restrict__ bn1_v,
    const float* __restrict__ b2,
    const float* __restrict__ bn2_g, const float* __restrict__ bn2_b,
    const float* __restrict__ bn2_m, const float* __restrict__ bn2_v,
    const float4* __restrict__ d1r, float* __restrict__ part) {
  __shared__ unsigned short s2_lds[K2 * SLD];  // 8704 B
  __shared__ float s1l[2][K1];
  __shared__ float4 gp[K1];                    // (b1, bn1_scale, bn1_off, -)
  __shared__ float r_lds[NN];
  __shared__ float p2[3 * K2];
  __shared__ float red[12];

  int blk = blockIdx.x;
  int b = blk & 31, tg = blk >> 5;   // tg-major
  int t0 = tg * 2;
  int tid = threadIdx.x;
  int lane = tid & 63, wave = tid >> 6;
  int l15 = lane & 15, l4 = lane >> 4;

  // ---- register A-fragments (phase 2) direct from global apad (L2-hot) ----
  const unsigned short* ab = apad + (size_t)b * NN * ALD;
  short8 afrag[4][2];
#pragma unroll
  for (int kt = 0; kt < 4; ++kt)
#pragma unroll
    for (int it = 0; it < 2; ++it) {
      int i = (wave * 2 + it) * 16 + l15;
      afrag[kt][it] = *((const short8*)&ab[i * ALD + kt * 32 + l4 * 8]);
    }
  // ---- w2 B-fragments direct from global w2t ----
  short8 bw[2][2];
#pragma unroll
  for (int kt = 0; kt < 2; ++kt) {
    bw[kt][0] = *((const short8*)&w2t[(0 + l15) * WLD + kt * 32 + l4 * 8]);
    bw[kt][1] = *((const short8*)&w2t[(16 + l15) * WLD + kt * 32 + l4 * 8]);
  }

  if (tid < 128) ((float*)s1l)[tid] = s1g[((size_t)b * TT + t0) * K1 + tid];
  if (tid < K1) {
    float s = bn1_g[tid] * rsqrtf(bn1_v[tid] + EPSV);
    gp[tid] = make_float4(b1[tid], s, bn1_b[tid] - bn1_m[tid] * s, 0.f);
  }
  if (tid >= 64 && tid < 192) r_lds[tid - 64] = rsum[b * NN + (tid - 64)];
  if (tid >= 192 && tid < 192 + K2) {
    int m = tid - 192;
    float s = bn2_g[m] * rsqrtf(bn2_v[m] + EPSV);
    p2[m] = b2[m];
    p2[K2 + m] = s;
    p2[2 * K2 + m] = bn2_b[m] - bn2_m[m] * s;
  }
  __syncthreads();

  f32x4 z4 = {0.f, 0.f, 0.f, 0.f};
  float rj0 = r_lds[(wave * 2 + 0) * 16 + l15];
  float rj1 = r_lds[(wave * 2 + 1) * 16 + l15];

  float c0 = 0.f, c1 = 0.f, c2 = 0.f;

  for (int ti = 0; ti < 2; ++ti) {
    int t = t0 + ti;
    // ---- phase 1: g1 frags in-register, MFMA -> sup2 ----
    f32x4 a1[2][2];
    a1[0][0] = z4; a1[0][1] = z4; a1[1][0] = z4; a1[1][1] = z4;
#pragma unroll
    for (int kt = 0; kt < 2; ++kt) {
      float4 gpv[8];
      float s1v[8];
#pragma unroll
      for (int e = 0; e < 8; ++e) {
        gpv[e] = gp[kt * 32 + l4 * 8 + e];
        s1v[e] = s1l[ti][kt * 32 + l4 * 8 + e];
      }
#pragma unroll
      for (int jt = 0; jt < 2; ++jt) {
        float rj = jt ? rj1 : rj0;
        short8 af;
#pragma unroll
        for (int e = 0; e < 8; ++e) {
          float4 p = gpv[e];
          float v = leaky_(rj * s1v[e] + p.x) * p.y + p.z;
          af[e] = (short)f2bf(v);
        }
        a1[jt][0] = __builtin_amdgcn_mfma_f32_16x16x32_bf16(af, bw[kt][0], a1[jt][0], 0, 0, 0);
        a1[jt][1] = __builtin_amdgcn_mfma_f32_16x16x32_bf16(af, bw[kt][1], a1[jt][1], 0, 0, 0);
      }
    }
    __syncthreads();   // (a) previous t's phase-2 s2_lds reads complete
#pragma unroll
    for (int jt = 0; jt < 2; ++jt) {
      int jbase = (wave * 2 + jt) * 16 + l4 * 4;
#pragma unroll
      for (int mt = 0; mt < 2; ++mt) {
        int m = mt * 16 + l15;
        unsigned lo = (unsigned)f2bf(a1[jt][mt][0]) | ((unsigned)f2bf(a1[jt][mt][1]) << 16);
        unsigned hi = (unsigned)f2bf(a1[jt][mt][2]) | ((unsigned)f2bf(a1[jt][mt][3]) << 16);
        uint2 val; val.x = lo; val.y = hi;
        *((uint2*)&s2_lds[m * SLD + jbase]) = val;
      }
    }
    __syncthreads();   // (b) s2 visible

    // ---- phase 2: g2 = a @ sup2 (register A-frags), fused leaky+BN2+d1 dot ----
    f32x4 acc[2][2];
    acc[0][0] = z4; acc[0][1] = z4; acc[1][0] = z4; acc[1][1] = z4;
#pragma unroll
    for (int kt = 0; kt < 4; ++kt) {
      short8 bfrag0 = *((const short8*)&s2_lds[(0 + l15) * SLD + kt * 32 + l4 * 8]);
      short8 bfrag1 = *((const short8*)&s2_lds[(16 + l15) * SLD + kt * 32 + l4 * 8]);
#pragma unroll
      for (int it = 0; it < 2; ++it) {
        acc[it][0] = __builtin_amdgcn_mfma_f32_16x16x32_bf16(afrag[kt][it], bfrag0, acc[it][0], 0, 0, 0);
        acc[it][1] = __builtin_amdgcn_mfma_f32_16x16x32_bf16(afrag[kt][it], bfrag1, acc[it][1], 0, 0, 0);
      }
    }
    float gv[2][2][4];
#pragma unroll
    for (int it = 0; it < 2; ++it)
#pragma unroll
      for (int mt = 0; mt < 2; ++mt) {
        int m = mt * 16 + l15;
        float bb = p2[m], bs = p2[K2 + m], bo = p2[2 * K2 + m];
#pragma unroll
        for (int r = 0; r < 4; ++r) gv[it][mt][r] = leaky_(acc[it][mt][r] + bb) * bs + bo;
      }
#pragma unroll
    for (int g = 0; g < 4; ++g) {
      int it = g >> 1, mt = g & 1;
      float4 v0 = d1r[(((size_t)t * 4 + g) * 3 + 0) * 256 + tid];
      float4 v1 = d1r[(((size_t)t * 4 + g) * 3 + 1) * 256 + tid];
      float4 v2 = d1r[(((size_t)t * 4 + g) * 3 + 2) * 256 + tid];
      c0 += gv[it][mt][0] * v0.x + gv[it][mt][1] * v0.y + gv[it][mt][2] * v0.z + gv[it][mt][3] * v0.w;
      c1 += gv[it][mt][0] * v1.x + gv[it][mt][1] * v1.y + gv[it][mt][2] * v1.z + gv[it][mt][3] * v1.w;
      c2 += gv[it][mt][0] * v2.x + gv[it][mt][1] * v2.y + gv[it][mt][2] * v2.z + gv[it][mt][3] * v2.w;
    }
  }

#pragma unroll
  for (int off = 32; off >= 1; off >>= 1) {
    c0 += __shfl_down(c0, off);
    c1 += __shfl_down(c1, off);
    c2 += __shfl_down(c2, off);
  }
  if (lane == 0) { red[wave * 3 + 0] = c0; red[wave * 3 + 1] = c1; red[wave * 3 + 2] = c2; }
  __syncthreads();
  if (tid == 0) {
    float s0 = 0.f, s1v = 0.f, s2v = 0.f;
    for (int w = 0; w < 4; ++w) { s0 += red[w * 3]; s1v += red[w * 3 + 1]; s2v += red[w * 3 + 2]; }
    part[((size_t)b * 32 + tg) * 3 + 0] = s0;
    part[((size_t)b * 32 + tg) * 3 + 1] = s1v;
    part[((size_t)b * 32 + tg) * 3 + 2] = s2v;
  }
}

// ---------------- final: reduce 32 partials, relu, d2 ----------------
__global__ __launch_bounds__(128) void k_out(const float* __restrict__ part,
                                             const float* __restrict__ d1b,
                                             const float* __restrict__ d2w,
                                             const float* __restrict__ d2b,
                                             float* __restrict__ out) {
  int b = blockIdx.x, n = threadIdx.x;
  float s[3] = {0.f, 0.f, 0.f};
  const float* p = part + (size_t)b * 32 * 3;
#pragma unroll
  for (int g = 0; g < 32; ++g) {
    s[0] += p[g * 3];
    s[1] += p[g * 3 + 1];
    s[2] += p[g * 3 + 2];
  }
  float o = d2b[n];
#pragma unroll
  for (int c = 0; c < 3; ++c) {
    float d = s[c] + d1b[c];
    d = d > 0.f ? d : 0.f;
    o += d * d2w[c * NN + n];
  }
  out[b * NN + n] = o;
}

extern "C" void kernel_launch(void* const* d_in, const int* in_sizes, int n_in,
                              void* d_out, int out_size, void* d_ws, size_t ws_size,
                              hipStream_t stream) {
  const float* x      = (const float*)d_in[0];
  const float* a      = (const float*)d_in[1];
  const float* lstm_k = (const float*)d_in[2];
  const float* lstm_r = (const float*)d_in[3];
  const float* lstm_b = (const float*)d_in[4];
  const float* bnl_g  = (const float*)d_in[5];
  const float* bnl_b  = (const float*)d_in[6];
  const float* bnl_m  = (const float*)d_in[7];
  const float* bnl_v  = (const float*)d_in[8];
  const float* w1     = (const float*)d_in[9];
  const float* b1     = (const float*)d_in[10];
  const float* bn1_g  = (const float*)d_in[11];
  const float* bn1_b  = (const float*)d_in[12];
  const float* bn1_m  = (const float*)d_in[13];
  const float* bn1_v  = (const float*)d_in[14];
  const float* w2     = (const float*)d_in[15];
  const float* b2     = (const float*)d_in[16];
  const float* bn2_g  = (const float*)d_in[17];
  const float* bn2_b  = (const float*)d_in[18];
  const float* bn2_m  = (const float*)d_in[19];
  const float* bn2_v  = (const float*)d_in[20];
  const float* d1_w   = (const float*)d_in[21];
  const float* d1_b   = (const float*)d_in[22];
  const float* d2_w   = (const float*)d_in[23];
  const float* d2_b   = (const float*)d_in[24];
  float* out = (float*)d_out;

  char* ws = (char*)d_ws;
  float* xz            = (float*)(ws + 0);                 // 2,097,152 B
  float* s1            = (float*)(ws + 2097152);           //   524,288 B
  float* rsum          = (float*)(ws + 2621440);           //    16,384 B
  float* part          = (float*)(ws + 2637824);           //    24,576 B
  unsigned short* apad = (unsigned short*)(ws + 2662400);  // 1,114,112 B
  unsigned short* w2t  = (unsigned short*)(ws + 3776512);  //     4,608 B
  unsigned* wrp        = (unsigned*)(ws + 3781120);        //    32,768 B
  unsigned* w1p        = (unsigned*)(ws + 3813888);        //     8,192 B
  float4* d1r          = (float4*)(ws + 3822080);          // 3,145,728 B

  k_xzp<<<258, 256, 0, stream>>>(x, lstm_k, lstm_b, lstm_r, w1, xz, wrp, w1p);
  k_mega<<<129, 256, 0, stream>>>(xz, wrp, w1p, bnl_g, bnl_b, bnl_m, bnl_v,
                                  a, w2, d1_w, s1, rsum, apad, w2t, d1r);
  k_gcn<<<1024, 256, 0, stream>>>(s1, rsum, apad, w2t, b1, bn1_g, bn1_b, bn1_m, bn1_v,
                                  b2, bn2_g, bn2_b, bn2_m, bn2_v, d1r, part);
  k_out<<<BB, 128, 0, stream>>>(part, d1_b, d2_w, d2_b, out);
}